// Round 17
// baseline (119.458 us; speedup 1.0000x reference)
//
#include <hip/hip_runtime.h>
#include <hip/hip_bf16.h>
#include <cstdint>
#include <cstddef>

typedef __bf16 bf16;
typedef __bf16 bf16x8 __attribute__((ext_vector_type(8)));
typedef float f32x4 __attribute__((ext_vector_type(4)));

#define NB 2
#define SEQ 2048
#define DM 1024
#define MTOK 4096   // NB*SEQ
#define DL 256
#define NH 16
#define HD 64

#define LOG2E 1.4426950408889634f

__device__ __forceinline__ void gload16(const void* g, void* l) {
  __builtin_amdgcn_global_load_lds((const __attribute__((address_space(1))) void*)g,
                                   (__attribute__((address_space(3))) void*)l, 16, 0, 0);
}
__device__ __forceinline__ float fast_exp2(float x) {
#if __has_builtin(__builtin_amdgcn_exp2f)
  return __builtin_amdgcn_exp2f(x);
#else
  float r; asm("v_exp_f32 %0, %1" : "=v"(r) : "v"(x)); return r;
#endif
}
// bijective XCD swizzle (m204): XCD x = orig%8 gets a contiguous work range
__device__ __forceinline__ int xcd_swz(int orig, int nwg) {
  int x = orig & 7;
  int q = nwg >> 3, r = nwg & 7;
  int base = (x < r) ? x * (q + 1) : r * (q + 1) + (x - r) * q;
  return base + (orig >> 3);
}

// ================= fused prep kernel (memory-only) =================
__device__ __forceinline__ void transpose_dev(const float* __restrict__ in0,
                                              bf16* __restrict__ out, int R, int C,
                                              int c0, int r0, int tid, float (*tile)[33]) {
  int tx = tid & 31, ty = tid >> 5;  // 32 x 8 load shape
#pragma unroll
  for (int i = 0; i < 4; ++i) {
    int r = r0 + ty + 8 * i;
    tile[ty + 8 * i][tx] = in0[(size_t)r * C + c0 + tx];
  }
  __syncthreads();
  // write shape: thread (c=tid>>3, s=tid&7) stores 4 bf16 along out row c
  int c = tid >> 3, s = tid & 7;
  bf16 o4[4] __attribute__((aligned(8)));
#pragma unroll
  for (int j = 0; j < 4; ++j) o4[j] = (bf16)tile[4 * s + j][c];
  *reinterpret_cast<uint2*>(out + (size_t)(c0 + c) * R + r0 + 4 * s) =
      *reinterpret_cast<const uint2*>(o4);
}

__device__ __forceinline__ void cvt8_dev(const float* __restrict__ in, bf16* __restrict__ out,
                                         int blk, int tid) {
  int i = (blk * 256 + tid) * 8;
  float4 a = *reinterpret_cast<const float4*>(in + i);
  float4 b = *reinterpret_cast<const float4*>(in + i + 4);
  bf16 o[8] __attribute__((aligned(16)));
  o[0] = (bf16)a.x; o[1] = (bf16)a.y; o[2] = (bf16)a.z; o[3] = (bf16)a.w;
  o[4] = (bf16)b.x; o[5] = (bf16)b.y; o[6] = (bf16)b.z; o[7] = (bf16)b.w;
  *reinterpret_cast<uint4*>(out + i) = *reinterpret_cast<const uint4*>(o);
}

__device__ __forceinline__ void sum8_dev(const float* __restrict__ in0, const float* __restrict__ in1,
                                         bf16* __restrict__ out, int blk, int tid) {
  int i = (blk * 256 + tid) * 8;
  float4 a0 = *reinterpret_cast<const float4*>(in0 + i);
  float4 b0 = *reinterpret_cast<const float4*>(in0 + i + 4);
  float4 a1 = *reinterpret_cast<const float4*>(in1 + i);
  float4 b1 = *reinterpret_cast<const float4*>(in1 + i + 4);
  bf16 o[8] __attribute__((aligned(16)));
  o[0] = (bf16)(a0.x + a1.x); o[1] = (bf16)(a0.y + a1.y);
  o[2] = (bf16)(a0.z + a1.z); o[3] = (bf16)(a0.w + a1.w);
  o[4] = (bf16)(b0.x + b1.x); o[5] = (bf16)(b0.y + b1.y);
  o[6] = (bf16)(b0.z + b1.z); o[7] = (bf16)(b0.w + b1.w);
  *reinterpret_cast<uint4*>(out + i) = *reinterpret_cast<const uint4*>(o);
}

__global__ __launch_bounds__(256) void prep_kernel(const float* __restrict__ x,
                                                   const float* __restrict__ Wq,
                                                   const float* __restrict__ Wk,
                                                   const float* __restrict__ Wv,
                                                   const float* __restrict__ Wo,
                                                   const float* __restrict__ Wdn,
                                                   const float* __restrict__ Wuk,
                                                   const float* __restrict__ Wuv,
                                                   bf16* xbf, bf16* WqT, bf16* WoT, bf16* WdnT,
                                                   bf16* WukT, bf16* WuvT, bf16* Wkv) {
  __shared__ float tile[32][33];
  int id = blockIdx.x, tid = threadIdx.x;
  if (id < 2048) { cvt8_dev(x, xbf, id, tid); return; }
  id -= 2048;
  if (id < 512) { sum8_dev(Wk, Wv, Wkv, id, tid); return; }   // Wkv = bf16(Wk+Wv) row-major
  id -= 512;
  if (id < 1024) { transpose_dev(Wq, WqT, 1024, 1024, (id & 31) * 32, (id >> 5) * 32, tid, tile); return; }
  id -= 1024;
  if (id < 1024) { transpose_dev(Wo, WoT, 1024, 1024, (id & 31) * 32, (id >> 5) * 32, tid, tile); return; }
  id -= 1024;
  if (id < 256) { transpose_dev(Wdn, WdnT, 1024, 256, (id & 7) * 32, (id >> 3) * 32, tid, tile); return; }
  id -= 256;
  if (id < 256) { transpose_dev(Wuk, WukT, 256, 1024, (id & 31) * 32, (id >> 5) * 32, tid, tile); return; }
  id -= 256;
  transpose_dev(Wuv, WuvT, 256, 1024, (id & 31) * 32, (id >> 5) * 32, tid, tile);
}

// ================= 128x64 MFMA GEMM core, BK=64, XOR-swizzled LDS, 2-phase dbuf =================
// No setprio: m190 measured setprio negative on barrier-lockstep 2-phase GEMMs (T5 regime gate).
// EPI: 0 = bf16 row-major stride DM; 3 = f32 stride DM; 7 = bf16 row-major stride MTOK
template <int EPI>
__device__ __forceinline__ void gemm_core(const bf16* __restrict__ A, const bf16* __restrict__ Bt,
                                          bf16* __restrict__ O1, float* __restrict__ Of,
                                          int K, int bx, int by, bf16* As, bf16* Bs) {
  const int tid = threadIdx.x;
  const int lane = tid & 63;
  const int wv = tid >> 6;
  const int wr = wv >> 1, wc = wv & 1;
  const int row0 = bx * 128, col0 = by * 64;
  const int l15 = lane & 15;
  const int lg = lane >> 4;

  const int r0 = tid >> 3;
  const int ccs = (tid & 7) ^ (r0 & 7);          // pre-swizzled global chunk
  const bf16* aS = A + (size_t)(row0 + r0) * K + ccs * 8;
  const bf16* bS = Bt + (size_t)(col0 + r0) * K + ccs * 8;
  const int dA = tid * 8;

#pragma unroll
  for (int i = 0; i < 4; ++i) gload16(aS + (size_t)(32 * i) * K, As + dA + 2048 * i);
#pragma unroll
  for (int j = 0; j < 2; ++j) gload16(bS + (size_t)(32 * j) * K, Bs + dA + 2048 * j);
  aS += 64; bS += 64;

  int aoff[4][2], boff[2][2];
#pragma unroll
  for (int m = 0; m < 4; ++m) {
    int ra = wr * 64 + m * 16 + l15;
#pragma unroll
    for (int kk = 0; kk < 2; ++kk)
      aoff[m][kk] = ra * 64 + (((kk * 4 + lg) ^ (ra & 7)) * 8);
  }
#pragma unroll
  for (int n = 0; n < 2; ++n) {
    int rb = wc * 32 + n * 16 + l15;
#pragma unroll
    for (int kk = 0; kk < 2; ++kk)
      boff[n][kk] = rb * 64 + (((kk * 4 + lg) ^ (rb & 7)) * 8);
  }

  f32x4 acc[4][2] = {};
  int cur = 0;
  for (int k0 = 0; k0 < K; k0 += 64) {
    __syncthreads();
    if (k0 + 64 < K) {
      const int nxA = (cur ^ 1) * 8192, nxB = (cur ^ 1) * 4096;
#pragma unroll
      for (int i = 0; i < 4; ++i) gload16(aS + (size_t)(32 * i) * K, As + nxA + dA + 2048 * i);
#pragma unroll
      for (int j = 0; j < 2; ++j) gload16(bS + (size_t)(32 * j) * K, Bs + nxB + dA + 2048 * j);
      aS += 64; bS += 64;
    }
    const bf16* Ab = As + cur * 8192;
    const bf16* Bb = Bs + cur * 4096;
    bf16x8 af[4][2], bfr[2][2];
#pragma unroll
    for (int m = 0; m < 4; ++m)
#pragma unroll
      for (int kk = 0; kk < 2; ++kk)
        af[m][kk] = *reinterpret_cast<const bf16x8*>(&Ab[aoff[m][kk]]);
#pragma unroll
    for (int n = 0; n < 2; ++n)
#pragma unroll
      for (int kk = 0; kk < 2; ++kk)
        bfr[n][kk] = *reinterpret_cast<const bf16x8*>(&Bb[boff[n][kk]]);
#pragma unroll
    for (int kk = 0; kk < 2; ++kk)
#pragma unroll
      for (int m = 0; m < 4; ++m)
#pragma unroll
        for (int n = 0; n < 2; ++n)
          acc[m][n] = __builtin_amdgcn_mfma_f32_16x16x32_bf16(af[m][kk], bfr[n][kk], acc[m][n], 0, 0, 0);
    cur ^= 1;
  }

  const int rbase = row0 + wr * 64 + (lane >> 4) * 4;
  const int cbase = col0 + wc * 32 + l15;
#pragma unroll
  for (int m = 0; m < 4; ++m) {
#pragma unroll
    for (int n = 0; n < 2; ++n) {
      const int cc = cbase + n * 16;
      if constexpr (EPI == 0) {
#pragma unroll
        for (int r = 0; r < 4; ++r)
          O1[(size_t)(rbase + m * 16 + r) * DM + cc] = (bf16)acc[m][n][r];
      } else if constexpr (EPI == 3) {
#pragma unroll
        for (int r = 0; r < 4; ++r)
          Of[(size_t)(rbase + m * 16 + r) * DM + cc] = acc[m][n][r];
      } else {  // EPI == 7: [d][tok], stride MTOK
#pragma unroll
        for (int r = 0; r < 4; ++r)
          O1[(size_t)(rbase + m * 16 + r) * MTOK + cc] = (bf16)acc[m][n][r];
      }
    }
  }
}

// ================= 64x64 MFMA GEMM core (latent), BK=64, swizzled, no setprio =================
__device__ __forceinline__ void gemm64_lat(const bf16* __restrict__ A, const bf16* __restrict__ Bt,
                                           bf16* __restrict__ O1, float* __restrict__ Of,
                                           int K, int bx, int by, bf16* As, bf16* Bs) {
  const int tid = threadIdx.x;
  const int lane = tid & 63;
  const int wv = tid >> 6;
  const int wr = wv >> 1, wc = wv & 1;
  const int row0 = bx * 64, col0 = by * 64;
  const int l15 = lane & 15;
  const int lg = lane >> 4;

  const int r0 = tid >> 3;
  const int ccs = (tid & 7) ^ (r0 & 7);
  const bf16* aS = A + (size_t)(row0 + r0) * K + ccs * 8;
  const bf16* bS = Bt + (size_t)(col0 + r0) * K + ccs * 8;
  const int dA = tid * 8;

#pragma unroll
  for (int j = 0; j < 2; ++j) {
    gload16(aS + (size_t)(32 * j) * K, As + dA + 2048 * j);
    gload16(bS + (size_t)(32 * j) * K, Bs + dA + 2048 * j);
  }
  aS += 64; bS += 64;

  int aoff[2][2], boff[2][2];
#pragma unroll
  for (int m = 0; m < 2; ++m) {
    int ra = wr * 32 + m * 16 + l15;
    int rb = wc * 32 + m * 16 + l15;
#pragma unroll
    for (int kk = 0; kk < 2; ++kk) {
      aoff[m][kk] = ra * 64 + (((kk * 4 + lg) ^ (ra & 7)) * 8);
      boff[m][kk] = rb * 64 + (((kk * 4 + lg) ^ (rb & 7)) * 8);
    }
  }

  f32x4 acc[2][2] = {};
  int cur = 0;
  for (int k0 = 0; k0 < K; k0 += 64) {
    __syncthreads();
    if (k0 + 64 < K) {
      const int nx = (cur ^ 1) * 4096;
#pragma unroll
      for (int j = 0; j < 2; ++j) {
        gload16(aS + (size_t)(32 * j) * K, As + nx + dA + 2048 * j);
        gload16(bS + (size_t)(32 * j) * K, Bs + nx + dA + 2048 * j);
      }
      aS += 64; bS += 64;
    }
    const bf16* Ab = As + cur * 4096;
    const bf16* Bb = Bs + cur * 4096;
    bf16x8 af[2][2], bfr[2][2];
#pragma unroll
    for (int m = 0; m < 2; ++m)
#pragma unroll
      for (int kk = 0; kk < 2; ++kk) {
        af[m][kk] = *reinterpret_cast<const bf16x8*>(&Ab[aoff[m][kk]]);
        bfr[m][kk] = *reinterpret_cast<const bf16x8*>(&Bb[boff[m][kk]]);
      }
#pragma unroll
    for (int kk = 0; kk < 2; ++kk)
#pragma unroll
      for (int m = 0; m < 2; ++m)
#pragma unroll
        for (int n = 0; n < 2; ++n)
          acc[m][n] = __builtin_amdgcn_mfma_f32_16x16x32_bf16(af[m][kk], bfr[n][kk], acc[m][n], 0, 0, 0);
    cur ^= 1;
  }

  const int rbase = row0 + wr * 32 + (lane >> 4) * 4;
  const int cbase = col0 + wc * 32 + l15;
#pragma unroll
  for (int m = 0; m < 2; ++m)
#pragma unroll
    for (int n = 0; n < 2; ++n)
#pragma unroll
      for (int r = 0; r < 4; ++r) {
        float v = acc[m][n][r];
        O1[(size_t)(rbase + m * 16 + r) * DL + (cbase + n * 16)] = (bf16)v;
        Of[(size_t)(rbase + m * 16 + r) * DL + (cbase + n * 16)] = v;
      }
}

// q = x @ Wq (512) + WkvdT = Wdn^T @ (Wk+Wv)^T (32, hidden inside); XCD-swizzled
__global__ __launch_bounds__(256) void gemm_q_w(const bf16* __restrict__ xbf,
                                                const bf16* __restrict__ WqT, bf16* qbf,
                                                const bf16* __restrict__ WdnT,
                                                const bf16* __restrict__ Wkv, bf16* WkvdT) {
  __shared__ __align__(16) bf16 As[2 * 8192];
  __shared__ __align__(16) bf16 Bs[2 * 4096];
  int id = xcd_swz(blockIdx.x, 544);
  if (id < 32)
    gemm_core<0>(WdnT, Wkv, WkvdT, nullptr, DM, id >> 4, id & 15, As, Bs);
  else {
    int j = id - 32;
    gemm_core<0>(xbf, WqT, qbf, nullptr, DM, j >> 4, j & 15, As, Bs);
  }
}

// latent = x @ Wkvd : 64x64 tiles -> 64x4 = 256 blocks (1/CU)
__global__ __launch_bounds__(256) void gemm_latent(const bf16* __restrict__ xbf,
                                                   const bf16* __restrict__ WkvdT,
                                                   bf16* latbf, float* out_lat) {
  __shared__ __align__(16) bf16 As[2 * 4096];
  __shared__ __align__(16) bf16 Bs[2 * 4096];
  int id = xcd_swz(blockIdx.x, 256);
  gemm64_lat(xbf, WkvdT, latbf, out_lat, DM, id >> 2, id & 3, As, Bs);
}

// L4: ids 0-511: k_rec = latent @ Wuk ; ids 512-1023: vT = Wuv^T @ latent^T
__global__ __launch_bounds__(256) void gemm_up(const bf16* __restrict__ latbf,
                                               const bf16* __restrict__ WukT,
                                               const bf16* __restrict__ WuvT,
                                               bf16* kbuf, bf16* vT) {
  __shared__ __align__(16) bf16 As[2 * 8192];
  __shared__ __align__(16) bf16 Bs[2 * 4096];
  int id = xcd_swz(blockIdx.x, 1024);
  if (id < 512)
    gemm_core<0>(latbf, WukT, kbuf, nullptr, DL, id >> 4, id & 15, As, Bs);
  else {
    int j = id - 512;
    gemm_core<7>(WuvT, latbf, vT, nullptr, DL, j >> 6, j & 63, As, Bs);
  }
}

// out0 = ctx @ Wo : N=1024 -> 512 blocks
__global__ __launch_bounds__(256) void gemm_out(const bf16* __restrict__ ctx,
                                                const bf16* __restrict__ WoT, float* out0) {
  __shared__ __align__(16) bf16 As[2 * 8192];
  __shared__ __align__(16) bf16 Bs[2 * 4096];
  int id = xcd_swz(blockIdx.x, 512);
  gemm_core<3>(ctx, WoT, nullptr, out0, DM, id >> 4, id & 15, As, Bs);
}

// ====== flash attention: 16 waves x 16 q = 256 q/block (round-16 proven, frozen) ======
__global__ __launch_bounds__(1024) void attn_kernel(const bf16* __restrict__ Q,
                                                    const bf16* __restrict__ Kr,
                                                    const bf16* __restrict__ Vt,
                                                    bf16* __restrict__ Ctx) {
  __shared__ __align__(16) bf16 Ks[2 * 4096];
  __shared__ __align__(16) bf16 Vs[2 * 4096];
  __shared__ __align__(16) bf16 Ps[16384];     // 16 waves x 16 q x 64 keys, XOR-swizzled
  const int work = xcd_swz(blockIdx.x, SEQ / 256 * NH * NB);   // 256
  const int qt = work & 7, h = (work >> 3) & 15, b = work >> 7;
  const int tid = threadIdx.x, lane = tid & 63, wv = tid >> 6;  // wv 0..15
  const int l15 = lane & 15, lg = lane >> 4;
  const int qbase = qt * 256 + wv * 16;
  const size_t tok0 = (size_t)b * SEQ;

  bf16x8 qf[2];
  {
    const bf16* qp = Q + (tok0 + qbase + l15) * DM + h * HD + lg * 8;
    qf[0] = *reinterpret_cast<const bf16x8*>(qp);
    qf[1] = *reinterpret_cast<const bf16x8*>(qp + 32);
  }

  // staging: 1024 threads x 1 chunk; tid<512 -> K chunk, else V chunk (wave-uniform split)
  const int cS = tid & 511;
  const int r0s = cS >> 3;
  const int cc0 = (cS & 7) ^ (r0s & 7);
  const bool isK = tid < 512;
  const bf16* src0 = isK ? (Kr + (tok0 + r0s) * DM + h * HD + cc0 * 8)
                         : (Vt + (size_t)(h * HD + r0s) * MTOK + tok0 + cc0 * 8);
  bf16* const dstBase = isK ? Ks : Vs;
  const int stepSrc = isK ? 64 * DM : 64;
  const int d0 = cS * 8;

  gload16(src0, dstBase + d0);
  src0 += stepSrc;

  int koff[2][4], poffw[4], poffr[2];
  const int hsw = l15 & 7;
#pragma unroll
  for (int ks = 0; ks < 2; ++ks)
#pragma unroll
    for (int nf = 0; nf < 4; ++nf) {
      int row = nf * 16 + l15;
      koff[ks][nf] = row * 64 + (((ks * 4 + lg) ^ (row & 7)) * 8);
    }
  const int psBase = wv * 1024 + l15 * 64;
#pragma unroll
  for (int nf = 0; nf < 4; ++nf)
    poffw[nf] = psBase + (((nf * 2 + (lg >> 1)) ^ hsw) * 8) + (lg & 1) * 4;
#pragma unroll
  for (int ks = 0; ks < 2; ++ks)
    poffr[ks] = psBase + (((ks * 4 + lg) ^ hsw) * 8);

  bf16x8 ones;
#pragma unroll
  for (int j = 0; j < 8; ++j) ones[j] = (bf16)1.0f;

  f32x4 oacc[4] = {};
  f32x4 lacc = {};
  float dec[4][4];
  const float DEC2C = (1.0f / 32.0f) * LOG2E;
  const float NC2 = -1.0e-4f * LOG2E;
  const float E64 = 0.99362048f, IE64 = 1.00642051f;
  const int ib = -qbase - l15 + lg * 4;

  int cur = 0;
  for (int t = 0; t < SEQ / 64; ++t) {
    const int key0 = t * 64;
    __syncthreads();
    if (t + 1 < SEQ / 64) {
      const int nx = (cur ^ 1) * 4096;
      gload16(src0, dstBase + nx + d0);
      src0 += stepSrc;
    }
    {
      bool before = (key0 + 63 < qbase);
      bool afterp = (key0 >= qbase + 79);
      if (t == 0 || (!before && !afterp)) {
#pragma unroll
        for (int nf = 0; nf < 4; ++nf)
#pragma unroll
          for (int r = 0; r < 4; ++r) {
            float df = (float)(key0 + ib + nf * 16 + r);
            dec[nf][r] = DEC2C * fast_exp2(NC2 * fabsf(df));
          }
      } else {
        float mlt = before ? IE64 : E64;
#pragma unroll
        for (int nf = 0; nf < 4; ++nf)
#pragma unroll
          for (int r = 0; r < 4; ++r) dec[nf][r] *= mlt;
      }
    }
    const int kb = cur * 4096;

    // S^T[key][q] = K @ Q^T
    f32x4 sc[4] = {};
    __builtin_amdgcn_s_setprio(1);
#pragma unroll
    for (int ks = 0; ks < 2; ++ks)
#pragma unroll
      for (int nf = 0; nf < 4; ++nf) {
        bf16x8 kf = *reinterpret_cast<const bf16x8*>(&Ks[kb + koff[ks][nf]]);
        sc[nf] = __builtin_amdgcn_mfma_f32_16x16x32_bf16(kf, qf[ks], sc[nf], 0, 0, 0);
      }
    __builtin_amdgcn_s_setprio(0);

    // p = exp2(s * dec); pack to bf16, store to swizzled Ps
#pragma unroll
    for (int nf = 0; nf < 4; ++nf) {
      bf16 t4[4] __attribute__((aligned(8)));
#pragma unroll
      for (int r = 0; r < 4; ++r) t4[r] = (bf16)fast_exp2(sc[nf][r] * dec[nf][r]);
      *reinterpret_cast<uint2*>(&Ps[poffw[nf]]) = *reinterpret_cast<const uint2*>(t4);
    }
    bf16x8 pb[2];
    pb[0] = *reinterpret_cast<const bf16x8*>(&Ps[poffr[0]]);
    pb[1] = *reinterpret_cast<const bf16x8*>(&Ps[poffr[1]]);

    // O^T += V^T @ P^T ; row-sums via ones-MFMA
    __builtin_amdgcn_s_setprio(1);
#pragma unroll
    for (int ks = 0; ks < 2; ++ks) {
#pragma unroll
      for (int nf = 0; nf < 4; ++nf) {
        bf16x8 vf = *reinterpret_cast<const bf16x8*>(&Vs[kb + koff[ks][nf]]);
        oacc[nf] = __builtin_amdgcn_mfma_f32_16x16x32_bf16(vf, pb[ks], oacc[nf], 0, 0, 0);
      }
      lacc = __builtin_amdgcn_mfma_f32_16x16x32_bf16(ones, pb[ks], lacc, 0, 0, 0);
    }
    __builtin_amdgcn_s_setprio(0);
    cur ^= 1;
  }

  const float inv = 1.0f / lacc[0];
#pragma unroll
  for (int nf = 0; nf < 4; ++nf) {
    bf16 o4[4] __attribute__((aligned(8)));
#pragma unroll
    for (int r = 0; r < 4; ++r) o4[r] = (bf16)(oacc[nf][r] * inv);
    *reinterpret_cast<uint2*>(Ctx + (tok0 + qbase + l15) * DM + h * HD + nf * 16 + lg * 4) =
        *reinterpret_cast<const uint2*>(o4);
  }
}

// ================= launch =================
extern "C" void kernel_launch(void* const* d_in, const int* in_sizes, int n_in,
                              void* d_out, int out_size, void* d_ws, size_t ws_size,
                              hipStream_t stream) {
  const float* x   = (const float*)d_in[0];
  const float* Wq  = (const float*)d_in[1];
  const float* Wk  = (const float*)d_in[2];
  const float* Wv  = (const float*)d_in[3];
  const float* Wo  = (const float*)d_in[4];
  const float* Wdn = (const float*)d_in[5];
  const float* Wuk = (const float*)d_in[6];
  const float* Wuv = (const float*)d_in[7];
  float* out0 = (float*)d_out;                     // [4096][1024] f32
  float* out_lat = out0 + (size_t)MTOK * DM;       // [4096][256]  f32

  char* ws = (char*)d_ws;
  const size_t MB = 1u << 20;
  bf16* xbf   = (bf16*)(ws + 0);            // 8 MiB; reused as ctx
  bf16* qbf   = (bf16*)(ws + 8 * MB);       // 8 MiB
  bf16* kbuf  = (bf16*)(ws + 16 * MB);      // 8 MiB: k_rec (L4+); Wkv alias before L4
  bf16* Wkv   = kbuf;                       //   [16,18) Wkv bf16 [1024][1024] (dead after L2)
  bf16* WkvdT = (bf16*)(ws + 18 * MB);      //   [18,18.5) WkvdT [256][1024] (dead after L3)
  bf16* vT    = (bf16*)(ws + 24 * MB);      // 8 MiB: v_rec^T [1024][4096]
  bf16* latbf = (bf16*)(ws + 32 * MB);      // 2 MiB [4096][256]
  bf16* WqT   = (bf16*)(ws + 34 * MB);      // 2 MiB [1024][1024]
  bf16* WoT   = (bf16*)(ws + 36 * MB);      // 2 MiB
  bf16* WukT  = (bf16*)(ws + 38 * MB);      // 512 KiB [1024][256]
  bf16* WuvT  = (bf16*)(ws + 38 * MB + 512 * 1024);  // 512 KiB [1024][256]
  bf16* WdnT  = (bf16*)(ws + 39 * MB);      // 512 KiB [256][1024]
  bf16* ctx   = xbf;

  // L1: prep (memory-only; 32x32 transposes + sum8)
  prep_kernel<<<5376, 256, 0, stream>>>(x, Wq, Wk, Wv, Wo, Wdn, Wuk, Wuv,
                                        xbf, WqT, WoT, WdnT, WukT, WuvT, Wkv);
  // L2: q = x@Wq (512) + WkvdT = Wdn^T@(Wk+Wv)^T (32, hidden)
  gemm_q_w<<<544, 256, 0, stream>>>(xbf, WqT, qbf, WdnT, Wkv, WkvdT);
  // L3: latent = x @ Wkvd (64x64 tiles, 256 blocks)
  gemm_latent<<<256, 256, 0, stream>>>(xbf, WkvdT, latbf, out_lat);
  // L4: k_rec = latent @ Wuk ; vT = Wuv^T @ latent^T
  gemm_up<<<1024, 256, 0, stream>>>(latbf, WukT, WuvT, kbuf, vT);
  // L5: attention (16 waves, 256 q/block, 256 blocks)
  attn_kernel<<<256, 1024, 0, stream>>>(qbf, kbuf, vT, ctx);
  // L6: out0 = ctx @ Wo
  gemm_out<<<512, 256, 0, stream>>>(ctx, WoT, out0);

  (void)in_sizes; (void)n_in; (void)out_size; (void)ws_size;
}

// Round 18
// 113.983 us; speedup vs baseline: 1.0480x; 1.0480x over previous
//
#include <hip/hip_runtime.h>
#include <hip/hip_bf16.h>
#include <cstdint>
#include <cstddef>

typedef __bf16 bf16;
typedef __bf16 bf16x8 __attribute__((ext_vector_type(8)));
typedef float f32x4 __attribute__((ext_vector_type(4)));

#define NB 2
#define SEQ 2048
#define DM 1024
#define MTOK 4096   // NB*SEQ
#define DL 256
#define NH 16
#define HD 64

#define LOG2E 1.4426950408889634f

__device__ __forceinline__ void gload16(const void* g, void* l) {
  __builtin_amdgcn_global_load_lds((const __attribute__((address_space(1))) void*)g,
                                   (__attribute__((address_space(3))) void*)l, 16, 0, 0);
}
__device__ __forceinline__ float fast_exp2(float x) {
#if __has_builtin(__builtin_amdgcn_exp2f)
  return __builtin_amdgcn_exp2f(x);
#else
  float r; asm("v_exp_f32 %0, %1" : "=v"(r) : "v"(x)); return r;
#endif
}
// bijective XCD swizzle (m204): XCD x = orig%8 gets a contiguous work range
__device__ __forceinline__ int xcd_swz(int orig, int nwg) {
  int x = orig & 7;
  int q = nwg >> 3, r = nwg & 7;
  int base = (x < r) ? x * (q + 1) : r * (q + 1) + (x - r) * q;
  return base + (orig >> 3);
}

// ================= fused prep kernel (memory-only) =================
__device__ __forceinline__ void transpose_dev(const float* __restrict__ in0,
                                              bf16* __restrict__ out, int R, int C,
                                              int c0, int r0, int tid, float (*tile)[33]) {
  int tx = tid & 31, ty = tid >> 5;  // 32 x 8 load shape
#pragma unroll
  for (int i = 0; i < 4; ++i) {
    int r = r0 + ty + 8 * i;
    tile[ty + 8 * i][tx] = in0[(size_t)r * C + c0 + tx];
  }
  __syncthreads();
  // write shape: thread (c=tid>>3, s=tid&7) stores 4 bf16 along out row c
  int c = tid >> 3, s = tid & 7;
  bf16 o4[4] __attribute__((aligned(8)));
#pragma unroll
  for (int j = 0; j < 4; ++j) o4[j] = (bf16)tile[4 * s + j][c];
  *reinterpret_cast<uint2*>(out + (size_t)(c0 + c) * R + r0 + 4 * s) =
      *reinterpret_cast<const uint2*>(o4);
}

__device__ __forceinline__ void cvt8_dev(const float* __restrict__ in, bf16* __restrict__ out,
                                         int blk, int tid) {
  int i = (blk * 256 + tid) * 8;
  float4 a = *reinterpret_cast<const float4*>(in + i);
  float4 b = *reinterpret_cast<const float4*>(in + i + 4);
  bf16 o[8] __attribute__((aligned(16)));
  o[0] = (bf16)a.x; o[1] = (bf16)a.y; o[2] = (bf16)a.z; o[3] = (bf16)a.w;
  o[4] = (bf16)b.x; o[5] = (bf16)b.y; o[6] = (bf16)b.z; o[7] = (bf16)b.w;
  *reinterpret_cast<uint4*>(out + i) = *reinterpret_cast<const uint4*>(o);
}

__device__ __forceinline__ void sum8_dev(const float* __restrict__ in0, const float* __restrict__ in1,
                                         bf16* __restrict__ out, int blk, int tid) {
  int i = (blk * 256 + tid) * 8;
  float4 a0 = *reinterpret_cast<const float4*>(in0 + i);
  float4 b0 = *reinterpret_cast<const float4*>(in0 + i + 4);
  float4 a1 = *reinterpret_cast<const float4*>(in1 + i);
  float4 b1 = *reinterpret_cast<const float4*>(in1 + i + 4);
  bf16 o[8] __attribute__((aligned(16)));
  o[0] = (bf16)(a0.x + a1.x); o[1] = (bf16)(a0.y + a1.y);
  o[2] = (bf16)(a0.z + a1.z); o[3] = (bf16)(a0.w + a1.w);
  o[4] = (bf16)(b0.x + b1.x); o[5] = (bf16)(b0.y + b1.y);
  o[6] = (bf16)(b0.z + b1.z); o[7] = (bf16)(b0.w + b1.w);
  *reinterpret_cast<uint4*>(out + i) = *reinterpret_cast<const uint4*>(o);
}

__global__ __launch_bounds__(256) void prep_kernel(const float* __restrict__ x,
                                                   const float* __restrict__ Wq,
                                                   const float* __restrict__ Wk,
                                                   const float* __restrict__ Wv,
                                                   const float* __restrict__ Wo,
                                                   const float* __restrict__ Wdn,
                                                   const float* __restrict__ Wuk,
                                                   const float* __restrict__ Wuv,
                                                   bf16* xbf, bf16* WqT, bf16* WoT, bf16* WdnT,
                                                   bf16* WukT, bf16* WuvT, bf16* Wkv) {
  __shared__ float tile[32][33];
  int id = blockIdx.x, tid = threadIdx.x;
  if (id < 2048) { cvt8_dev(x, xbf, id, tid); return; }
  id -= 2048;
  if (id < 512) { sum8_dev(Wk, Wv, Wkv, id, tid); return; }   // Wkv = bf16(Wk+Wv) row-major
  id -= 512;
  if (id < 1024) { transpose_dev(Wq, WqT, 1024, 1024, (id & 31) * 32, (id >> 5) * 32, tid, tile); return; }
  id -= 1024;
  if (id < 1024) { transpose_dev(Wo, WoT, 1024, 1024, (id & 31) * 32, (id >> 5) * 32, tid, tile); return; }
  id -= 1024;
  if (id < 256) { transpose_dev(Wdn, WdnT, 1024, 256, (id & 7) * 32, (id >> 3) * 32, tid, tile); return; }
  id -= 256;
  if (id < 256) { transpose_dev(Wuk, WukT, 256, 1024, (id & 31) * 32, (id >> 5) * 32, tid, tile); return; }
  id -= 256;
  transpose_dev(Wuv, WuvT, 256, 1024, (id & 31) * 32, (id >> 5) * 32, tid, tile);
}

// ================= 128x64 MFMA GEMM core, BK=64, XOR-swizzled LDS, 2-phase dbuf =================
// setprio around MFMA clusters: +5.7 us fleet-wide (r16 vs r17 controlled A/B) — multi-block/CU
// gives wave role-diversity, so T5 pays here.
// EPI: 0 = bf16 row-major stride DM; 3 = f32 stride DM; 7 = bf16 row-major stride MTOK
template <int EPI>
__device__ __forceinline__ void gemm_core(const bf16* __restrict__ A, const bf16* __restrict__ Bt,
                                          bf16* __restrict__ O1, float* __restrict__ Of,
                                          int K, int bx, int by, bf16* As, bf16* Bs) {
  const int tid = threadIdx.x;
  const int lane = tid & 63;
  const int wv = tid >> 6;
  const int wr = wv >> 1, wc = wv & 1;
  const int row0 = bx * 128, col0 = by * 64;
  const int l15 = lane & 15;
  const int lg = lane >> 4;

  const int r0 = tid >> 3;
  const int ccs = (tid & 7) ^ (r0 & 7);          // pre-swizzled global chunk
  const bf16* aS = A + (size_t)(row0 + r0) * K + ccs * 8;
  const bf16* bS = Bt + (size_t)(col0 + r0) * K + ccs * 8;
  const int dA = tid * 8;

#pragma unroll
  for (int i = 0; i < 4; ++i) gload16(aS + (size_t)(32 * i) * K, As + dA + 2048 * i);
#pragma unroll
  for (int j = 0; j < 2; ++j) gload16(bS + (size_t)(32 * j) * K, Bs + dA + 2048 * j);
  aS += 64; bS += 64;

  int aoff[4][2], boff[2][2];
#pragma unroll
  for (int m = 0; m < 4; ++m) {
    int ra = wr * 64 + m * 16 + l15;
#pragma unroll
    for (int kk = 0; kk < 2; ++kk)
      aoff[m][kk] = ra * 64 + (((kk * 4 + lg) ^ (ra & 7)) * 8);
  }
#pragma unroll
  for (int n = 0; n < 2; ++n) {
    int rb = wc * 32 + n * 16 + l15;
#pragma unroll
    for (int kk = 0; kk < 2; ++kk)
      boff[n][kk] = rb * 64 + (((kk * 4 + lg) ^ (rb & 7)) * 8);
  }

  f32x4 acc[4][2] = {};
  int cur = 0;
  for (int k0 = 0; k0 < K; k0 += 64) {
    __syncthreads();
    if (k0 + 64 < K) {
      const int nxA = (cur ^ 1) * 8192, nxB = (cur ^ 1) * 4096;
#pragma unroll
      for (int i = 0; i < 4; ++i) gload16(aS + (size_t)(32 * i) * K, As + nxA + dA + 2048 * i);
#pragma unroll
      for (int j = 0; j < 2; ++j) gload16(bS + (size_t)(32 * j) * K, Bs + nxB + dA + 2048 * j);
      aS += 64; bS += 64;
    }
    const bf16* Ab = As + cur * 8192;
    const bf16* Bb = Bs + cur * 4096;
    bf16x8 af[4][2], bfr[2][2];
#pragma unroll
    for (int m = 0; m < 4; ++m)
#pragma unroll
      for (int kk = 0; kk < 2; ++kk)
        af[m][kk] = *reinterpret_cast<const bf16x8*>(&Ab[aoff[m][kk]]);
#pragma unroll
    for (int n = 0; n < 2; ++n)
#pragma unroll
      for (int kk = 0; kk < 2; ++kk)
        bfr[n][kk] = *reinterpret_cast<const bf16x8*>(&Bb[boff[n][kk]]);
    __builtin_amdgcn_s_setprio(1);
#pragma unroll
    for (int kk = 0; kk < 2; ++kk)
#pragma unroll
      for (int m = 0; m < 4; ++m)
#pragma unroll
        for (int n = 0; n < 2; ++n)
          acc[m][n] = __builtin_amdgcn_mfma_f32_16x16x32_bf16(af[m][kk], bfr[n][kk], acc[m][n], 0, 0, 0);
    __builtin_amdgcn_s_setprio(0);
    cur ^= 1;
  }

  const int rbase = row0 + wr * 64 + (lane >> 4) * 4;
  const int cbase = col0 + wc * 32 + l15;
#pragma unroll
  for (int m = 0; m < 4; ++m) {
#pragma unroll
    for (int n = 0; n < 2; ++n) {
      const int cc = cbase + n * 16;
      if constexpr (EPI == 0) {
#pragma unroll
        for (int r = 0; r < 4; ++r)
          O1[(size_t)(rbase + m * 16 + r) * DM + cc] = (bf16)acc[m][n][r];
      } else if constexpr (EPI == 3) {
#pragma unroll
        for (int r = 0; r < 4; ++r)
          Of[(size_t)(rbase + m * 16 + r) * DM + cc] = acc[m][n][r];
      } else {  // EPI == 7: [d][tok], stride MTOK
#pragma unroll
        for (int r = 0; r < 4; ++r)
          O1[(size_t)(rbase + m * 16 + r) * MTOK + cc] = (bf16)acc[m][n][r];
      }
    }
  }
}

// ================= 64x64 MFMA GEMM core (latent), BK=64, swizzled =================
__device__ __forceinline__ void gemm64_lat(const bf16* __restrict__ A, const bf16* __restrict__ Bt,
                                           bf16* __restrict__ O1, float* __restrict__ Of,
                                           int K, int bx, int by, bf16* As, bf16* Bs) {
  const int tid = threadIdx.x;
  const int lane = tid & 63;
  const int wv = tid >> 6;
  const int wr = wv >> 1, wc = wv & 1;
  const int row0 = bx * 64, col0 = by * 64;
  const int l15 = lane & 15;
  const int lg = lane >> 4;

  const int r0 = tid >> 3;
  const int ccs = (tid & 7) ^ (r0 & 7);
  const bf16* aS = A + (size_t)(row0 + r0) * K + ccs * 8;
  const bf16* bS = Bt + (size_t)(col0 + r0) * K + ccs * 8;
  const int dA = tid * 8;

#pragma unroll
  for (int j = 0; j < 2; ++j) {
    gload16(aS + (size_t)(32 * j) * K, As + dA + 2048 * j);
    gload16(bS + (size_t)(32 * j) * K, Bs + dA + 2048 * j);
  }
  aS += 64; bS += 64;

  int aoff[2][2], boff[2][2];
#pragma unroll
  for (int m = 0; m < 2; ++m) {
    int ra = wr * 32 + m * 16 + l15;
    int rb = wc * 32 + m * 16 + l15;
#pragma unroll
    for (int kk = 0; kk < 2; ++kk) {
      aoff[m][kk] = ra * 64 + (((kk * 4 + lg) ^ (ra & 7)) * 8);
      boff[m][kk] = rb * 64 + (((kk * 4 + lg) ^ (rb & 7)) * 8);
    }
  }

  f32x4 acc[2][2] = {};
  int cur = 0;
  for (int k0 = 0; k0 < K; k0 += 64) {
    __syncthreads();
    if (k0 + 64 < K) {
      const int nx = (cur ^ 1) * 4096;
#pragma unroll
      for (int j = 0; j < 2; ++j) {
        gload16(aS + (size_t)(32 * j) * K, As + nx + dA + 2048 * j);
        gload16(bS + (size_t)(32 * j) * K, Bs + nx + dA + 2048 * j);
      }
      aS += 64; bS += 64;
    }
    const bf16* Ab = As + cur * 4096;
    const bf16* Bb = Bs + cur * 4096;
    bf16x8 af[2][2], bfr[2][2];
#pragma unroll
    for (int m = 0; m < 2; ++m)
#pragma unroll
      for (int kk = 0; kk < 2; ++kk) {
        af[m][kk] = *reinterpret_cast<const bf16x8*>(&Ab[aoff[m][kk]]);
        bfr[m][kk] = *reinterpret_cast<const bf16x8*>(&Bb[boff[m][kk]]);
      }
    __builtin_amdgcn_s_setprio(1);
#pragma unroll
    for (int kk = 0; kk < 2; ++kk)
#pragma unroll
      for (int m = 0; m < 2; ++m)
#pragma unroll
        for (int n = 0; n < 2; ++n)
          acc[m][n] = __builtin_amdgcn_mfma_f32_16x16x32_bf16(af[m][kk], bfr[n][kk], acc[m][n], 0, 0, 0);
    __builtin_amdgcn_s_setprio(0);
    cur ^= 1;
  }

  const int rbase = row0 + wr * 32 + (lane >> 4) * 4;
  const int cbase = col0 + wc * 32 + l15;
#pragma unroll
  for (int m = 0; m < 2; ++m)
#pragma unroll
    for (int n = 0; n < 2; ++n)
#pragma unroll
      for (int r = 0; r < 4; ++r) {
        float v = acc[m][n][r];
        O1[(size_t)(rbase + m * 16 + r) * DL + (cbase + n * 16)] = (bf16)v;
        Of[(size_t)(rbase + m * 16 + r) * DL + (cbase + n * 16)] = v;
      }
}

// q = x @ Wq (512) + WkvdT = Wdn^T @ (Wk+Wv)^T (32, hidden inside); XCD-swizzled
__global__ __launch_bounds__(256) void gemm_q_w(const bf16* __restrict__ xbf,
                                                const bf16* __restrict__ WqT, bf16* qbf,
                                                const bf16* __restrict__ WdnT,
                                                const bf16* __restrict__ Wkv, bf16* WkvdT) {
  __shared__ __align__(16) bf16 As[2 * 8192];
  __shared__ __align__(16) bf16 Bs[2 * 4096];
  int id = xcd_swz(blockIdx.x, 544);
  if (id < 32)
    gemm_core<0>(WdnT, Wkv, WkvdT, nullptr, DM, id >> 4, id & 15, As, Bs);
  else {
    int j = id - 32;
    gemm_core<0>(xbf, WqT, qbf, nullptr, DM, j >> 4, j & 15, As, Bs);
  }
}

// latent = x @ Wkvd : 64x64 tiles -> 64x4 = 256 blocks (1/CU)
__global__ __launch_bounds__(256) void gemm_latent(const bf16* __restrict__ xbf,
                                                   const bf16* __restrict__ WkvdT,
                                                   bf16* latbf, float* out_lat) {
  __shared__ __align__(16) bf16 As[2 * 4096];
  __shared__ __align__(16) bf16 Bs[2 * 4096];
  int id = xcd_swz(blockIdx.x, 256);
  gemm64_lat(xbf, WkvdT, latbf, out_lat, DM, id >> 2, id & 3, As, Bs);
}

// L4: ids 0-511: k_rec = latent @ Wuk ; ids 512-1023: vT = Wuv^T @ latent^T
__global__ __launch_bounds__(256) void gemm_up(const bf16* __restrict__ latbf,
                                               const bf16* __restrict__ WukT,
                                               const bf16* __restrict__ WuvT,
                                               bf16* kbuf, bf16* vT) {
  __shared__ __align__(16) bf16 As[2 * 8192];
  __shared__ __align__(16) bf16 Bs[2 * 4096];
  int id = xcd_swz(blockIdx.x, 1024);
  if (id < 512)
    gemm_core<0>(latbf, WukT, kbuf, nullptr, DL, id >> 4, id & 15, As, Bs);
  else {
    int j = id - 512;
    gemm_core<7>(WuvT, latbf, vT, nullptr, DL, j >> 6, j & 63, As, Bs);
  }
}

// out0 = ctx @ Wo : N=1024 -> 512 blocks
__global__ __launch_bounds__(256) void gemm_out(const bf16* __restrict__ ctx,
                                                const bf16* __restrict__ WoT, float* out0) {
  __shared__ __align__(16) bf16 As[2 * 8192];
  __shared__ __align__(16) bf16 Bs[2 * 4096];
  int id = xcd_swz(blockIdx.x, 512);
  gemm_core<3>(ctx, WoT, nullptr, out0, DM, id >> 4, id & 15, As, Bs);
}

// ====== flash attention: 16 waves x 16 q = 256 q/block (round-16 proven, frozen) ======
__global__ __launch_bounds__(1024) void attn_kernel(const bf16* __restrict__ Q,
                                                    const bf16* __restrict__ Kr,
                                                    const bf16* __restrict__ Vt,
                                                    bf16* __restrict__ Ctx) {
  __shared__ __align__(16) bf16 Ks[2 * 4096];
  __shared__ __align__(16) bf16 Vs[2 * 4096];
  __shared__ __align__(16) bf16 Ps[16384];     // 16 waves x 16 q x 64 keys, XOR-swizzled
  const int work = xcd_swz(blockIdx.x, SEQ / 256 * NH * NB);   // 256
  const int qt = work & 7, h = (work >> 3) & 15, b = work >> 7;
  const int tid = threadIdx.x, lane = tid & 63, wv = tid >> 6;  // wv 0..15
  const int l15 = lane & 15, lg = lane >> 4;
  const int qbase = qt * 256 + wv * 16;
  const size_t tok0 = (size_t)b * SEQ;

  bf16x8 qf[2];
  {
    const bf16* qp = Q + (tok0 + qbase + l15) * DM + h * HD + lg * 8;
    qf[0] = *reinterpret_cast<const bf16x8*>(qp);
    qf[1] = *reinterpret_cast<const bf16x8*>(qp + 32);
  }

  // staging: 1024 threads x 1 chunk; tid<512 -> K chunk, else V chunk (wave-uniform split)
  const int cS = tid & 511;
  const int r0s = cS >> 3;
  const int cc0 = (cS & 7) ^ (r0s & 7);
  const bool isK = tid < 512;
  const bf16* src0 = isK ? (Kr + (tok0 + r0s) * DM + h * HD + cc0 * 8)
                         : (Vt + (size_t)(h * HD + r0s) * MTOK + tok0 + cc0 * 8);
  bf16* const dstBase = isK ? Ks : Vs;
  const int stepSrc = isK ? 64 * DM : 64;
  const int d0 = cS * 8;

  gload16(src0, dstBase + d0);
  src0 += stepSrc;

  int koff[2][4], poffw[4], poffr[2];
  const int hsw = l15 & 7;
#pragma unroll
  for (int ks = 0; ks < 2; ++ks)
#pragma unroll
    for (int nf = 0; nf < 4; ++nf) {
      int row = nf * 16 + l15;
      koff[ks][nf] = row * 64 + (((ks * 4 + lg) ^ (row & 7)) * 8);
    }
  const int psBase = wv * 1024 + l15 * 64;
#pragma unroll
  for (int nf = 0; nf < 4; ++nf)
    poffw[nf] = psBase + (((nf * 2 + (lg >> 1)) ^ hsw) * 8) + (lg & 1) * 4;
#pragma unroll
  for (int ks = 0; ks < 2; ++ks)
    poffr[ks] = psBase + (((ks * 4 + lg) ^ hsw) * 8);

  bf16x8 ones;
#pragma unroll
  for (int j = 0; j < 8; ++j) ones[j] = (bf16)1.0f;

  f32x4 oacc[4] = {};
  f32x4 lacc = {};
  float dec[4][4];
  const float DEC2C = (1.0f / 32.0f) * LOG2E;
  const float NC2 = -1.0e-4f * LOG2E;
  const float E64 = 0.99362048f, IE64 = 1.00642051f;
  const int ib = -qbase - l15 + lg * 4;

  int cur = 0;
  for (int t = 0; t < SEQ / 64; ++t) {
    const int key0 = t * 64;
    __syncthreads();
    if (t + 1 < SEQ / 64) {
      const int nx = (cur ^ 1) * 4096;
      gload16(src0, dstBase + nx + d0);
      src0 += stepSrc;
    }
    {
      bool before = (key0 + 63 < qbase);
      bool afterp = (key0 >= qbase + 79);
      if (t == 0 || (!before && !afterp)) {
#pragma unroll
        for (int nf = 0; nf < 4; ++nf)
#pragma unroll
          for (int r = 0; r < 4; ++r) {
            float df = (float)(key0 + ib + nf * 16 + r);
            dec[nf][r] = DEC2C * fast_exp2(NC2 * fabsf(df));
          }
      } else {
        float mlt = before ? IE64 : E64;
#pragma unroll
        for (int nf = 0; nf < 4; ++nf)
#pragma unroll
          for (int r = 0; r < 4; ++r) dec[nf][r] *= mlt;
      }
    }
    const int kb = cur * 4096;

    // S^T[key][q] = K @ Q^T
    f32x4 sc[4] = {};
    __builtin_amdgcn_s_setprio(1);
#pragma unroll
    for (int ks = 0; ks < 2; ++ks)
#pragma unroll
      for (int nf = 0; nf < 4; ++nf) {
        bf16x8 kf = *reinterpret_cast<const bf16x8*>(&Ks[kb + koff[ks][nf]]);
        sc[nf] = __builtin_amdgcn_mfma_f32_16x16x32_bf16(kf, qf[ks], sc[nf], 0, 0, 0);
      }
    __builtin_amdgcn_s_setprio(0);

    // p = exp2(s * dec); pack to bf16, store to swizzled Ps
#pragma unroll
    for (int nf = 0; nf < 4; ++nf) {
      bf16 t4[4] __attribute__((aligned(8)));
#pragma unroll
      for (int r = 0; r < 4; ++r) t4[r] = (bf16)fast_exp2(sc[nf][r] * dec[nf][r]);
      *reinterpret_cast<uint2*>(&Ps[poffw[nf]]) = *reinterpret_cast<const uint2*>(t4);
    }
    bf16x8 pb[2];
    pb[0] = *reinterpret_cast<const bf16x8*>(&Ps[poffr[0]]);
    pb[1] = *reinterpret_cast<const bf16x8*>(&Ps[poffr[1]]);

    // O^T += V^T @ P^T ; row-sums via ones-MFMA
    __builtin_amdgcn_s_setprio(1);
#pragma unroll
    for (int ks = 0; ks < 2; ++ks) {
#pragma unroll
      for (int nf = 0; nf < 4; ++nf) {
        bf16x8 vf = *reinterpret_cast<const bf16x8*>(&Vs[kb + koff[ks][nf]]);
        oacc[nf] = __builtin_amdgcn_mfma_f32_16x16x32_bf16(vf, pb[ks], oacc[nf], 0, 0, 0);
      }
      lacc = __builtin_amdgcn_mfma_f32_16x16x32_bf16(ones, pb[ks], lacc, 0, 0, 0);
    }
    __builtin_amdgcn_s_setprio(0);
    cur ^= 1;
  }

  const float inv = 1.0f / lacc[0];
#pragma unroll
  for (int nf = 0; nf < 4; ++nf) {
    bf16 o4[4] __attribute__((aligned(8)));
#pragma unroll
    for (int r = 0; r < 4; ++r) o4[r] = (bf16)(oacc[nf][r] * inv);
    *reinterpret_cast<uint2*>(Ctx + (tok0 + qbase + l15) * DM + h * HD + nf * 16 + lg * 4) =
        *reinterpret_cast<const uint2*>(o4);
  }
}

// ================= launch =================
extern "C" void kernel_launch(void* const* d_in, const int* in_sizes, int n_in,
                              void* d_out, int out_size, void* d_ws, size_t ws_size,
                              hipStream_t stream) {
  const float* x   = (const float*)d_in[0];
  const float* Wq  = (const float*)d_in[1];
  const float* Wk  = (const float*)d_in[2];
  const float* Wv  = (const float*)d_in[3];
  const float* Wo  = (const float*)d_in[4];
  const float* Wdn = (const float*)d_in[5];
  const float* Wuk = (const float*)d_in[6];
  const float* Wuv = (const float*)d_in[7];
  float* out0 = (float*)d_out;                     // [4096][1024] f32
  float* out_lat = out0 + (size_t)MTOK * DM;       // [4096][256]  f32

  char* ws = (char*)d_ws;
  const size_t MB = 1u << 20;
  bf16* xbf   = (bf16*)(ws + 0);            // 8 MiB; reused as ctx
  bf16* qbf   = (bf16*)(ws + 8 * MB);       // 8 MiB
  bf16* kbuf  = (bf16*)(ws + 16 * MB);      // 8 MiB: k_rec (L4+); Wkv alias before L4
  bf16* Wkv   = kbuf;                       //   [16,18) Wkv bf16 [1024][1024] (dead after L2)
  bf16* WkvdT = (bf16*)(ws + 18 * MB);      //   [18,18.5) WkvdT [256][1024] (dead after L3)
  bf16* vT    = (bf16*)(ws + 24 * MB);      // 8 MiB: v_rec^T [1024][4096]
  bf16* latbf = (bf16*)(ws + 32 * MB);      // 2 MiB [4096][256]
  bf16* WqT   = (bf16*)(ws + 34 * MB);      // 2 MiB [1024][1024]
  bf16* WoT   = (bf16*)(ws + 36 * MB);      // 2 MiB
  bf16* WukT  = (bf16*)(ws + 38 * MB);      // 512 KiB [1024][256]
  bf16* WuvT  = (bf16*)(ws + 38 * MB + 512 * 1024);  // 512 KiB [1024][256]
  bf16* WdnT  = (bf16*)(ws + 39 * MB);      // 512 KiB [256][1024]
  bf16* ctx   = xbf;

  // L1: prep (memory-only; 32x32 transposes + sum8)
  prep_kernel<<<5376, 256, 0, stream>>>(x, Wq, Wk, Wv, Wo, Wdn, Wuk, Wuv,
                                        xbf, WqT, WoT, WdnT, WukT, WuvT, Wkv);
  // L2: q = x@Wq (512) + WkvdT = Wdn^T@(Wk+Wv)^T (32, hidden)
  gemm_q_w<<<544, 256, 0, stream>>>(xbf, WqT, qbf, WdnT, Wkv, WkvdT);
  // L3: latent = x @ Wkvd (64x64 tiles, 256 blocks)
  gemm_latent<<<256, 256, 0, stream>>>(xbf, WkvdT, latbf, out_lat);
  // L4: k_rec = latent @ Wuk ; vT = Wuv^T @ latent^T
  gemm_up<<<1024, 256, 0, stream>>>(latbf, WukT, WuvT, kbuf, vT);
  // L5: attention (16 waves, 256 q/block, 256 blocks)
  attn_kernel<<<256, 1024, 0, stream>>>(qbf, kbuf, vT, ctx);
  // L6: out0 = ctx @ Wo
  gemm_out<<<512, 256, 0, stream>>>(ctx, WoT, out0);

  (void)in_sizes; (void)n_in; (void)out_size; (void)ws_size;
}

// Round 19
// 112.129 us; speedup vs baseline: 1.0654x; 1.0165x over previous
//
#include <hip/hip_runtime.h>
#include <hip/hip_bf16.h>
#include <cstdint>
#include <cstddef>

typedef __bf16 bf16;
typedef __bf16 bf16x8 __attribute__((ext_vector_type(8)));
typedef float f32x4 __attribute__((ext_vector_type(4)));

#define NB 2
#define SEQ 2048
#define DM 1024
#define MTOK 4096   // NB*SEQ
#define DL 256
#define NH 16
#define HD 64

#define LOG2E 1.4426950408889634f

__device__ __forceinline__ void gload16(const void* g, void* l) {
  __builtin_amdgcn_global_load_lds((const __attribute__((address_space(1))) void*)g,
                                   (__attribute__((address_space(3))) void*)l, 16, 0, 0);
}
__device__ __forceinline__ float fast_exp2(float x) {
#if __has_builtin(__builtin_amdgcn_exp2f)
  return __builtin_amdgcn_exp2f(x);
#else
  float r; asm("v_exp_f32 %0, %1" : "=v"(r) : "v"(x)); return r;
#endif
}
// bijective XCD swizzle (m204): XCD x = orig%8 gets a contiguous work range
__device__ __forceinline__ int xcd_swz(int orig, int nwg) {
  int x = orig & 7;
  int q = nwg >> 3, r = nwg & 7;
  int base = (x < r) ? x * (q + 1) : r * (q + 1) + (x - r) * q;
  return base + (orig >> 3);
}

// ================= fused prep kernel (memory-only) =================
__device__ __forceinline__ void transpose_dev(const float* __restrict__ in0,
                                              bf16* __restrict__ out, int R, int C,
                                              int c0, int r0, int tid, float (*tile)[33]) {
  int tx = tid & 31, ty = tid >> 5;  // 32 x 8 load shape
#pragma unroll
  for (int i = 0; i < 4; ++i) {
    int r = r0 + ty + 8 * i;
    tile[ty + 8 * i][tx] = in0[(size_t)r * C + c0 + tx];
  }
  __syncthreads();
  // write shape: thread (c=tid>>3, s=tid&7) stores 4 bf16 along out row c
  int c = tid >> 3, s = tid & 7;
  bf16 o4[4] __attribute__((aligned(8)));
#pragma unroll
  for (int j = 0; j < 4; ++j) o4[j] = (bf16)tile[4 * s + j][c];
  *reinterpret_cast<uint2*>(out + (size_t)(c0 + c) * R + r0 + 4 * s) =
      *reinterpret_cast<const uint2*>(o4);
}

__device__ __forceinline__ void cvt8_dev(const float* __restrict__ in, bf16* __restrict__ out,
                                         int blk, int tid) {
  int i = (blk * 256 + tid) * 8;
  float4 a = *reinterpret_cast<const float4*>(in + i);
  float4 b = *reinterpret_cast<const float4*>(in + i + 4);
  bf16 o[8] __attribute__((aligned(16)));
  o[0] = (bf16)a.x; o[1] = (bf16)a.y; o[2] = (bf16)a.z; o[3] = (bf16)a.w;
  o[4] = (bf16)b.x; o[5] = (bf16)b.y; o[6] = (bf16)b.z; o[7] = (bf16)b.w;
  *reinterpret_cast<uint4*>(out + i) = *reinterpret_cast<const uint4*>(o);
}

__device__ __forceinline__ void sum8_dev(const float* __restrict__ in0, const float* __restrict__ in1,
                                         bf16* __restrict__ out, int blk, int tid) {
  int i = (blk * 256 + tid) * 8;
  float4 a0 = *reinterpret_cast<const float4*>(in0 + i);
  float4 b0 = *reinterpret_cast<const float4*>(in0 + i + 4);
  float4 a1 = *reinterpret_cast<const float4*>(in1 + i);
  float4 b1 = *reinterpret_cast<const float4*>(in1 + i + 4);
  bf16 o[8] __attribute__((aligned(16)));
  o[0] = (bf16)(a0.x + a1.x); o[1] = (bf16)(a0.y + a1.y);
  o[2] = (bf16)(a0.z + a1.z); o[3] = (bf16)(a0.w + a1.w);
  o[4] = (bf16)(b0.x + b1.x); o[5] = (bf16)(b0.y + b1.y);
  o[6] = (bf16)(b0.z + b1.z); o[7] = (bf16)(b0.w + b1.w);
  *reinterpret_cast<uint4*>(out + i) = *reinterpret_cast<const uint4*>(o);
}

__global__ __launch_bounds__(256) void prep_kernel(const float* __restrict__ x,
                                                   const float* __restrict__ Wq,
                                                   const float* __restrict__ Wk,
                                                   const float* __restrict__ Wv,
                                                   const float* __restrict__ Wo,
                                                   const float* __restrict__ Wdn,
                                                   const float* __restrict__ Wuk,
                                                   const float* __restrict__ Wuv,
                                                   bf16* xbf, bf16* WqT, bf16* WoT, bf16* WdnT,
                                                   bf16* WukT, bf16* WuvT, bf16* Wkv) {
  __shared__ float tile[32][33];
  int id = blockIdx.x, tid = threadIdx.x;
  if (id < 2048) { cvt8_dev(x, xbf, id, tid); return; }
  id -= 2048;
  if (id < 512) { sum8_dev(Wk, Wv, Wkv, id, tid); return; }   // Wkv = bf16(Wk+Wv) row-major
  id -= 512;
  if (id < 1024) { transpose_dev(Wq, WqT, 1024, 1024, (id & 31) * 32, (id >> 5) * 32, tid, tile); return; }
  id -= 1024;
  if (id < 1024) { transpose_dev(Wo, WoT, 1024, 1024, (id & 31) * 32, (id >> 5) * 32, tid, tile); return; }
  id -= 1024;
  if (id < 256) { transpose_dev(Wdn, WdnT, 1024, 256, (id & 7) * 32, (id >> 3) * 32, tid, tile); return; }
  id -= 256;
  if (id < 256) { transpose_dev(Wuk, WukT, 256, 1024, (id & 31) * 32, (id >> 5) * 32, tid, tile); return; }
  id -= 256;
  transpose_dev(Wuv, WuvT, 256, 1024, (id & 31) * 32, (id >> 5) * 32, tid, tile);
}

// ================= 128x64 MFMA GEMM core, BK=64, XOR-swizzled LDS, 2-phase dbuf =================
// setprio around MFMA clusters: +5.7 us fleet-wide (r16 vs r17 controlled A/B).
// EPI: 0 = bf16 row-major stride DM; 3 = f32 stride DM; 7 = bf16 row-major stride MTOK
template <int EPI>
__device__ __forceinline__ void gemm_core(const bf16* __restrict__ A, const bf16* __restrict__ Bt,
                                          bf16* __restrict__ O1, float* __restrict__ Of,
                                          int K, int bx, int by, bf16* As, bf16* Bs) {
  const int tid = threadIdx.x;
  const int lane = tid & 63;
  const int wv = tid >> 6;
  const int wr = wv >> 1, wc = wv & 1;
  const int row0 = bx * 128, col0 = by * 64;
  const int l15 = lane & 15;
  const int lg = lane >> 4;

  const int r0 = tid >> 3;
  const int ccs = (tid & 7) ^ (r0 & 7);          // pre-swizzled global chunk
  const bf16* aS = A + (size_t)(row0 + r0) * K + ccs * 8;
  const bf16* bS = Bt + (size_t)(col0 + r0) * K + ccs * 8;
  const int dA = tid * 8;

#pragma unroll
  for (int i = 0; i < 4; ++i) gload16(aS + (size_t)(32 * i) * K, As + dA + 2048 * i);
#pragma unroll
  for (int j = 0; j < 2; ++j) gload16(bS + (size_t)(32 * j) * K, Bs + dA + 2048 * j);
  aS += 64; bS += 64;

  int aoff[4][2], boff[2][2];
#pragma unroll
  for (int m = 0; m < 4; ++m) {
    int ra = wr * 64 + m * 16 + l15;
#pragma unroll
    for (int kk = 0; kk < 2; ++kk)
      aoff[m][kk] = ra * 64 + (((kk * 4 + lg) ^ (ra & 7)) * 8);
  }
#pragma unroll
  for (int n = 0; n < 2; ++n) {
    int rb = wc * 32 + n * 16 + l15;
#pragma unroll
    for (int kk = 0; kk < 2; ++kk)
      boff[n][kk] = rb * 64 + (((kk * 4 + lg) ^ (rb & 7)) * 8);
  }

  f32x4 acc[4][2] = {};
  int cur = 0;
  for (int k0 = 0; k0 < K; k0 += 64) {
    __syncthreads();
    if (k0 + 64 < K) {
      const int nxA = (cur ^ 1) * 8192, nxB = (cur ^ 1) * 4096;
#pragma unroll
      for (int i = 0; i < 4; ++i) gload16(aS + (size_t)(32 * i) * K, As + nxA + dA + 2048 * i);
#pragma unroll
      for (int j = 0; j < 2; ++j) gload16(bS + (size_t)(32 * j) * K, Bs + nxB + dA + 2048 * j);
      aS += 64; bS += 64;
    }
    const bf16* Ab = As + cur * 8192;
    const bf16* Bb = Bs + cur * 4096;
    bf16x8 af[4][2], bfr[2][2];
#pragma unroll
    for (int m = 0; m < 4; ++m)
#pragma unroll
      for (int kk = 0; kk < 2; ++kk)
        af[m][kk] = *reinterpret_cast<const bf16x8*>(&Ab[aoff[m][kk]]);
#pragma unroll
    for (int n = 0; n < 2; ++n)
#pragma unroll
      for (int kk = 0; kk < 2; ++kk)
        bfr[n][kk] = *reinterpret_cast<const bf16x8*>(&Bb[boff[n][kk]]);
    __builtin_amdgcn_s_setprio(1);
#pragma unroll
    for (int kk = 0; kk < 2; ++kk)
#pragma unroll
      for (int m = 0; m < 4; ++m)
#pragma unroll
        for (int n = 0; n < 2; ++n)
          acc[m][n] = __builtin_amdgcn_mfma_f32_16x16x32_bf16(af[m][kk], bfr[n][kk], acc[m][n], 0, 0, 0);
    __builtin_amdgcn_s_setprio(0);
    cur ^= 1;
  }

  const int rbase = row0 + wr * 64 + (lane >> 4) * 4;
  const int cbase = col0 + wc * 32 + l15;
#pragma unroll
  for (int m = 0; m < 4; ++m) {
#pragma unroll
    for (int n = 0; n < 2; ++n) {
      const int cc = cbase + n * 16;
      if constexpr (EPI == 0) {
#pragma unroll
        for (int r = 0; r < 4; ++r)
          O1[(size_t)(rbase + m * 16 + r) * DM + cc] = (bf16)acc[m][n][r];
      } else if constexpr (EPI == 3) {
#pragma unroll
        for (int r = 0; r < 4; ++r)
          Of[(size_t)(rbase + m * 16 + r) * DM + cc] = acc[m][n][r];
      } else {  // EPI == 7: [d][tok], stride MTOK
#pragma unroll
        for (int r = 0; r < 4; ++r)
          O1[(size_t)(rbase + m * 16 + r) * MTOK + cc] = (bf16)acc[m][n][r];
      }
    }
  }
}

// ================= 64x64 MFMA GEMM core (latent), BK=64, swizzled =================
__device__ __forceinline__ void gemm64_lat(const bf16* __restrict__ A, const bf16* __restrict__ Bt,
                                           bf16* __restrict__ O1, float* __restrict__ Of,
                                           int K, int bx, int by, bf16* As, bf16* Bs) {
  const int tid = threadIdx.x;
  const int lane = tid & 63;
  const int wv = tid >> 6;
  const int wr = wv >> 1, wc = wv & 1;
  const int row0 = bx * 64, col0 = by * 64;
  const int l15 = lane & 15;
  const int lg = lane >> 4;

  const int r0 = tid >> 3;
  const int ccs = (tid & 7) ^ (r0 & 7);
  const bf16* aS = A + (size_t)(row0 + r0) * K + ccs * 8;
  const bf16* bS = Bt + (size_t)(col0 + r0) * K + ccs * 8;
  const int dA = tid * 8;

#pragma unroll
  for (int j = 0; j < 2; ++j) {
    gload16(aS + (size_t)(32 * j) * K, As + dA + 2048 * j);
    gload16(bS + (size_t)(32 * j) * K, Bs + dA + 2048 * j);
  }
  aS += 64; bS += 64;

  int aoff[2][2], boff[2][2];
#pragma unroll
  for (int m = 0; m < 2; ++m) {
    int ra = wr * 32 + m * 16 + l15;
    int rb = wc * 32 + m * 16 + l15;
#pragma unroll
    for (int kk = 0; kk < 2; ++kk) {
      aoff[m][kk] = ra * 64 + (((kk * 4 + lg) ^ (ra & 7)) * 8);
      boff[m][kk] = rb * 64 + (((kk * 4 + lg) ^ (rb & 7)) * 8);
    }
  }

  f32x4 acc[2][2] = {};
  int cur = 0;
  for (int k0 = 0; k0 < K; k0 += 64) {
    __syncthreads();
    if (k0 + 64 < K) {
      const int nx = (cur ^ 1) * 4096;
#pragma unroll
      for (int j = 0; j < 2; ++j) {
        gload16(aS + (size_t)(32 * j) * K, As + nx + dA + 2048 * j);
        gload16(bS + (size_t)(32 * j) * K, Bs + nx + dA + 2048 * j);
      }
      aS += 64; bS += 64;
    }
    const bf16* Ab = As + cur * 4096;
    const bf16* Bb = Bs + cur * 4096;
    bf16x8 af[2][2], bfr[2][2];
#pragma unroll
    for (int m = 0; m < 2; ++m)
#pragma unroll
      for (int kk = 0; kk < 2; ++kk) {
        af[m][kk] = *reinterpret_cast<const bf16x8*>(&Ab[aoff[m][kk]]);
        bfr[m][kk] = *reinterpret_cast<const bf16x8*>(&Bb[boff[m][kk]]);
      }
    __builtin_amdgcn_s_setprio(1);
#pragma unroll
    for (int kk = 0; kk < 2; ++kk)
#pragma unroll
      for (int m = 0; m < 2; ++m)
#pragma unroll
        for (int n = 0; n < 2; ++n)
          acc[m][n] = __builtin_amdgcn_mfma_f32_16x16x32_bf16(af[m][kk], bfr[n][kk], acc[m][n], 0, 0, 0);
    __builtin_amdgcn_s_setprio(0);
    cur ^= 1;
  }

  const int rbase = row0 + wr * 32 + (lane >> 4) * 4;
  const int cbase = col0 + wc * 32 + l15;
#pragma unroll
  for (int m = 0; m < 2; ++m)
#pragma unroll
    for (int n = 0; n < 2; ++n)
#pragma unroll
      for (int r = 0; r < 4; ++r) {
        float v = acc[m][n][r];
        O1[(size_t)(rbase + m * 16 + r) * DL + (cbase + n * 16)] = (bf16)v;
        Of[(size_t)(rbase + m * 16 + r) * DL + (cbase + n * 16)] = v;
      }
}

// q = x @ Wq (512) + WkvdT = Wdn^T @ (Wk+Wv)^T (32, hidden inside); XCD-swizzled
__global__ __launch_bounds__(256) void gemm_q_w(const bf16* __restrict__ xbf,
                                                const bf16* __restrict__ WqT, bf16* qbf,
                                                const bf16* __restrict__ WdnT,
                                                const bf16* __restrict__ Wkv, bf16* WkvdT) {
  __shared__ __align__(16) bf16 As[2 * 8192];
  __shared__ __align__(16) bf16 Bs[2 * 4096];
  int id = xcd_swz(blockIdx.x, 544);
  if (id < 32)
    gemm_core<0>(WdnT, Wkv, WkvdT, nullptr, DM, id >> 4, id & 15, As, Bs);
  else {
    int j = id - 32;
    gemm_core<0>(xbf, WqT, qbf, nullptr, DM, j >> 4, j & 15, As, Bs);
  }
}

// latent = x @ Wkvd : 64x64 tiles -> 64x4 = 256 blocks (1/CU)
__global__ __launch_bounds__(256) void gemm_latent(const bf16* __restrict__ xbf,
                                                   const bf16* __restrict__ WkvdT,
                                                   bf16* latbf, float* out_lat) {
  __shared__ __align__(16) bf16 As[2 * 4096];
  __shared__ __align__(16) bf16 Bs[2 * 4096];
  int id = xcd_swz(blockIdx.x, 256);
  gemm64_lat(xbf, WkvdT, latbf, out_lat, DM, id >> 2, id & 3, As, Bs);
}

// L4: ids 0-511: k_rec = latent @ Wuk ; ids 512-1023: vT = Wuv^T @ latent^T
__global__ __launch_bounds__(256) void gemm_up(const bf16* __restrict__ latbf,
                                               const bf16* __restrict__ WukT,
                                               const bf16* __restrict__ WuvT,
                                               bf16* kbuf, bf16* vT) {
  __shared__ __align__(16) bf16 As[2 * 8192];
  __shared__ __align__(16) bf16 Bs[2 * 4096];
  int id = xcd_swz(blockIdx.x, 1024);
  if (id < 512)
    gemm_core<0>(latbf, WukT, kbuf, nullptr, DL, id >> 4, id & 15, As, Bs);
  else {
    int j = id - 512;
    gemm_core<7>(WuvT, latbf, vT, nullptr, DL, j >> 6, j & 63, As, Bs);
  }
}

// out0 = ctx @ Wo : N=1024 -> 512 blocks
__global__ __launch_bounds__(256) void gemm_out(const bf16* __restrict__ ctx,
                                                const bf16* __restrict__ WoT, float* out0) {
  __shared__ __align__(16) bf16 As[2 * 8192];
  __shared__ __align__(16) bf16 Bs[2 * 4096];
  int id = xcd_swz(blockIdx.x, 512);
  gemm_core<3>(ctx, WoT, nullptr, out0, DM, id >> 4, id & 15, As, Bs);
}

// ====== flash attention: 16 waves x 256 q/block, KVBLK=128 (2 sub-tiles per barrier) ======
// Same per-sub-tile body as the proven r16 kernel; barriers 32 -> 16; occupancy invariant
// (grid = 1 block/CU regardless of LDS). 96 KB LDS.
__global__ __launch_bounds__(1024) void attn_kernel(const bf16* __restrict__ Q,
                                                    const bf16* __restrict__ Kr,
                                                    const bf16* __restrict__ Vt,
                                                    bf16* __restrict__ Ctx) {
  __shared__ __align__(16) bf16 Ks[2 * 8192];   // [dbuf][128 keys x 64 d], swizzled
  __shared__ __align__(16) bf16 Vs[2 * 8192];   // [dbuf][64 d x 128 keys], swizzled
  __shared__ __align__(16) bf16 Ps[16384];      // 16 waves x 16 q x 64 keys
  const int work = xcd_swz(blockIdx.x, SEQ / 256 * NH * NB);   // 256
  const int qt = work & 7, h = (work >> 3) & 15, b = work >> 7;
  const int tid = threadIdx.x, lane = tid & 63, wv = tid >> 6;  // wv 0..15
  const int l15 = lane & 15, lg = lane >> 4;
  const int qbase = qt * 256 + wv * 16;
  const size_t tok0 = (size_t)b * SEQ;

  bf16x8 qf[2];
  {
    const bf16* qp = Q + (tok0 + qbase + l15) * DM + h * HD + lg * 8;
    qf[0] = *reinterpret_cast<const bf16x8*>(qp);
    qf[1] = *reinterpret_cast<const bf16x8*>(qp + 32);
  }

  // staging: tid<512 -> K (2 chunks: rows r0s, r0s+64); else V (2 chunks: keys +0, +64)
  const int cS = tid & 511;
  const int r0s = cS >> 3;
  const int cc0 = (cS & 7) ^ (r0s & 7);
  const bool isK = tid < 512;
  const bf16* src0 = isK ? (Kr + (tok0 + r0s) * DM + h * HD + cc0 * 8)
                         : (Vt + (size_t)(h * HD + r0s) * MTOK + tok0 + cc0 * 8);
  bf16* const dstBase = isK ? Ks : Vs;
  const size_t sub2 = isK ? (size_t)64 * DM : 64;     // second sub-tile source offset
  const size_t stepSrc = isK ? (size_t)128 * DM : 128; // per-period advance
  const int d0 = cS * 8;

  // prologue: stage period 0 (both sub-tiles) into buf 0
  gload16(src0, dstBase + d0);
  gload16(src0 + sub2, dstBase + 4096 + d0);
  src0 += stepSrc;

  int koff[2][4], poffw[4], poffr[2];
  const int hsw = l15 & 7;
#pragma unroll
  for (int ks = 0; ks < 2; ++ks)
#pragma unroll
    for (int nf = 0; nf < 4; ++nf) {
      int row = nf * 16 + l15;
      koff[ks][nf] = row * 64 + (((ks * 4 + lg) ^ (row & 7)) * 8);
    }
  const int psBase = wv * 1024 + l15 * 64;
#pragma unroll
  for (int nf = 0; nf < 4; ++nf)
    poffw[nf] = psBase + (((nf * 2 + (lg >> 1)) ^ hsw) * 8) + (lg & 1) * 4;
#pragma unroll
  for (int ks = 0; ks < 2; ++ks)
    poffr[ks] = psBase + (((ks * 4 + lg) ^ hsw) * 8);

  bf16x8 ones;
#pragma unroll
  for (int j = 0; j < 8; ++j) ones[j] = (bf16)1.0f;

  f32x4 oacc[4] = {};
  f32x4 lacc = {};
  float dec[4][4];
  const float DEC2C = (1.0f / 32.0f) * LOG2E;
  const float NC2 = -1.0e-4f * LOG2E;
  const float E64 = 0.99362048f, IE64 = 1.00642051f;
  const int ib = -qbase - l15 + lg * 4;

  // dec for tile key0 = 0
#pragma unroll
  for (int nf = 0; nf < 4; ++nf)
#pragma unroll
    for (int r = 0; r < 4; ++r) {
      float df = (float)(ib + nf * 16 + r);
      dec[nf][r] = DEC2C * fast_exp2(NC2 * fabsf(df));
    }

  auto upd_dec = [&](int key0) {  // advance dec from tile (key0-64) to tile key0
    bool before = (key0 + 63 < qbase);
    bool afterp = (key0 >= qbase + 79);
    if (!before && !afterp) {
#pragma unroll
      for (int nf = 0; nf < 4; ++nf)
#pragma unroll
        for (int r = 0; r < 4; ++r) {
          float df = (float)(key0 + ib + nf * 16 + r);
          dec[nf][r] = DEC2C * fast_exp2(NC2 * fabsf(df));
        }
    } else {
      float mlt = before ? IE64 : E64;
#pragma unroll
      for (int nf = 0; nf < 4; ++nf)
#pragma unroll
        for (int r = 0; r < 4; ++r) dec[nf][r] *= mlt;
    }
  };

  // one 64-key sub-tile: QK -> softmax(Ps round-trip) -> PV + lsum (proven r16 body)
  auto body = [&](int kb) {
    f32x4 sc[4] = {};
    __builtin_amdgcn_s_setprio(1);
#pragma unroll
    for (int ks = 0; ks < 2; ++ks)
#pragma unroll
      for (int nf = 0; nf < 4; ++nf) {
        bf16x8 kf = *reinterpret_cast<const bf16x8*>(&Ks[kb + koff[ks][nf]]);
        sc[nf] = __builtin_amdgcn_mfma_f32_16x16x32_bf16(kf, qf[ks], sc[nf], 0, 0, 0);
      }
    __builtin_amdgcn_s_setprio(0);
#pragma unroll
    for (int nf = 0; nf < 4; ++nf) {
      bf16 t4[4] __attribute__((aligned(8)));
#pragma unroll
      for (int r = 0; r < 4; ++r) t4[r] = (bf16)fast_exp2(sc[nf][r] * dec[nf][r]);
      *reinterpret_cast<uint2*>(&Ps[poffw[nf]]) = *reinterpret_cast<const uint2*>(t4);
    }
    bf16x8 pb[2];
    pb[0] = *reinterpret_cast<const bf16x8*>(&Ps[poffr[0]]);
    pb[1] = *reinterpret_cast<const bf16x8*>(&Ps[poffr[1]]);
    __builtin_amdgcn_s_setprio(1);
#pragma unroll
    for (int ks = 0; ks < 2; ++ks) {
#pragma unroll
      for (int nf = 0; nf < 4; ++nf) {
        bf16x8 vf = *reinterpret_cast<const bf16x8*>(&Vs[kb + koff[ks][nf]]);
        oacc[nf] = __builtin_amdgcn_mfma_f32_16x16x32_bf16(vf, pb[ks], oacc[nf], 0, 0, 0);
      }
      lacc = __builtin_amdgcn_mfma_f32_16x16x32_bf16(ones, pb[ks], lacc, 0, 0, 0);
    }
    __builtin_amdgcn_s_setprio(0);
  };

  int cur = 0;
  for (int p = 0; p < 16; ++p) {
    __syncthreads();   // buf[cur] staged; buf[cur^1] reads drained
    if (p + 1 < 16) {
      const int nx = (cur ^ 1) * 8192;
      gload16(src0, dstBase + nx + d0);
      gload16(src0 + sub2, dstBase + nx + 4096 + d0);
      src0 += stepSrc;
    }
    const int kb = cur * 8192;
    body(kb);                    // sub-tile A, keys [128p, 128p+64)
    upd_dec(p * 128 + 64);
    body(kb + 4096);             // sub-tile B, keys [128p+64, 128p+128)
    if (p + 1 < 16) upd_dec((p + 1) * 128);
    cur ^= 1;
  }

  const float inv = 1.0f / lacc[0];
#pragma unroll
  for (int nf = 0; nf < 4; ++nf) {
    bf16 o4[4] __attribute__((aligned(8)));
#pragma unroll
    for (int r = 0; r < 4; ++r) o4[r] = (bf16)(oacc[nf][r] * inv);
    *reinterpret_cast<uint2*>(Ctx + (tok0 + qbase + l15) * DM + h * HD + nf * 16 + lg * 4) =
        *reinterpret_cast<const uint2*>(o4);
  }
}

// ================= launch =================
extern "C" void kernel_launch(void* const* d_in, const int* in_sizes, int n_in,
                              void* d_out, int out_size, void* d_ws, size_t ws_size,
                              hipStream_t stream) {
  const float* x   = (const float*)d_in[0];
  const float* Wq  = (const float*)d_in[1];
  const float* Wk  = (const float*)d_in[2];
  const float* Wv  = (const float*)d_in[3];
  const float* Wo  = (const float*)d_in[4];
  const float* Wdn = (const float*)d_in[5];
  const float* Wuk = (const float*)d_in[6];
  const float* Wuv = (const float*)d_in[7];
  float* out0 = (float*)d_out;                     // [4096][1024] f32
  float* out_lat = out0 + (size_t)MTOK * DM;       // [4096][256]  f32

  char* ws = (char*)d_ws;
  const size_t MB = 1u << 20;
  bf16* xbf   = (bf16*)(ws + 0);            // 8 MiB; reused as ctx
  bf16* qbf   = (bf16*)(ws + 8 * MB);       // 8 MiB
  bf16* kbuf  = (bf16*)(ws + 16 * MB);      // 8 MiB: k_rec (L4+); Wkv alias before L4
  bf16* Wkv   = kbuf;                       //   [16,18) Wkv bf16 [1024][1024] (dead after L2)
  bf16* WkvdT = (bf16*)(ws + 18 * MB);      //   [18,18.5) WkvdT [256][1024] (dead after L3)
  bf16* vT    = (bf16*)(ws + 24 * MB);      // 8 MiB: v_rec^T [1024][4096]
  bf16* latbf = (bf16*)(ws + 32 * MB);      // 2 MiB [4096][256]
  bf16* WqT   = (bf16*)(ws + 34 * MB);      // 2 MiB [1024][1024]
  bf16* WoT   = (bf16*)(ws + 36 * MB);      // 2 MiB
  bf16* WukT  = (bf16*)(ws + 38 * MB);      // 512 KiB [1024][256]
  bf16* WuvT  = (bf16*)(ws + 38 * MB + 512 * 1024);  // 512 KiB [1024][256]
  bf16* WdnT  = (bf16*)(ws + 39 * MB);      // 512 KiB [256][1024]
  bf16* ctx   = xbf;

  // L1: prep (memory-only; 32x32 transposes + sum8)
  prep_kernel<<<5376, 256, 0, stream>>>(x, Wq, Wk, Wv, Wo, Wdn, Wuk, Wuv,
                                        xbf, WqT, WoT, WdnT, WukT, WuvT, Wkv);
  // L2: q = x@Wq (512) + WkvdT = Wdn^T@(Wk+Wv)^T (32, hidden)
  gemm_q_w<<<544, 256, 0, stream>>>(xbf, WqT, qbf, WdnT, Wkv, WkvdT);
  // L3: latent = x @ Wkvd (64x64 tiles, 256 blocks)
  gemm_latent<<<256, 256, 0, stream>>>(xbf, WkvdT, latbf, out_lat);
  // L4: k_rec = latent @ Wuk ; vT = Wuv^T @ latent^T
  gemm_up<<<1024, 256, 0, stream>>>(latbf, WukT, WuvT, kbuf, vT);
  // L5: attention (16 waves, 256 q/block, KVBLK=128, 256 blocks)
  attn_kernel<<<256, 1024, 0, stream>>>(qbf, kbuf, vT, ctx);
  // L6: out0 = ctx @ Wo
  gemm_out<<<512, 256, 0, stream>>>(ctx, WoT, out0);

  (void)in_sizes; (void)n_in; (void)out_size; (void)ws_size;
}

// Round 20
// 112.057 us; speedup vs baseline: 1.0660x; 1.0006x over previous
//
#include <hip/hip_runtime.h>
#include <hip/hip_bf16.h>
#include <cstdint>
#include <cstddef>

typedef __bf16 bf16;
typedef __bf16 bf16x8 __attribute__((ext_vector_type(8)));
typedef float f32x4 __attribute__((ext_vector_type(4)));

#define NB 2
#define SEQ 2048
#define DM 1024
#define MTOK 4096   // NB*SEQ
#define DL 256
#define NH 16
#define HD 64

#define LOG2E 1.4426950408889634f

__device__ __forceinline__ void gload16(const void* g, void* l) {
  __builtin_amdgcn_global_load_lds((const __attribute__((address_space(1))) void*)g,
                                   (__attribute__((address_space(3))) void*)l, 16, 0, 0);
}
__device__ __forceinline__ float fast_exp2(float x) {
#if __has_builtin(__builtin_amdgcn_exp2f)
  return __builtin_amdgcn_exp2f(x);
#else
  float r; asm("v_exp_f32 %0, %1" : "=v"(r) : "v"(x)); return r;
#endif
}
// bijective XCD swizzle (m204): XCD x = orig%8 gets a contiguous work range
__device__ __forceinline__ int xcd_swz(int orig, int nwg) {
  int x = orig & 7;
  int q = nwg >> 3, r = nwg & 7;
  int base = (x < r) ? x * (q + 1) : r * (q + 1) + (x - r) * q;
  return base + (orig >> 3);
}

// ================= fused prep kernel (memory-only) =================
__device__ __forceinline__ void transpose_dev(const float* __restrict__ in0,
                                              bf16* __restrict__ out, int R, int C,
                                              int c0, int r0, int tid, float (*tile)[33]) {
  int tx = tid & 31, ty = tid >> 5;  // 32 x 8 load shape
#pragma unroll
  for (int i = 0; i < 4; ++i) {
    int r = r0 + ty + 8 * i;
    tile[ty + 8 * i][tx] = in0[(size_t)r * C + c0 + tx];
  }
  __syncthreads();
  // write shape: thread (c=tid>>3, s=tid&7) stores 4 bf16 along out row c
  int c = tid >> 3, s = tid & 7;
  bf16 o4[4] __attribute__((aligned(8)));
#pragma unroll
  for (int j = 0; j < 4; ++j) o4[j] = (bf16)tile[4 * s + j][c];
  *reinterpret_cast<uint2*>(out + (size_t)(c0 + c) * R + r0 + 4 * s) =
      *reinterpret_cast<const uint2*>(o4);
}

__device__ __forceinline__ void cvt8_dev(const float* __restrict__ in, bf16* __restrict__ out,
                                         int blk, int tid) {
  int i = (blk * 256 + tid) * 8;
  float4 a = *reinterpret_cast<const float4*>(in + i);
  float4 b = *reinterpret_cast<const float4*>(in + i + 4);
  bf16 o[8] __attribute__((aligned(16)));
  o[0] = (bf16)a.x; o[1] = (bf16)a.y; o[2] = (bf16)a.z; o[3] = (bf16)a.w;
  o[4] = (bf16)b.x; o[5] = (bf16)b.y; o[6] = (bf16)b.z; o[7] = (bf16)b.w;
  *reinterpret_cast<uint4*>(out + i) = *reinterpret_cast<const uint4*>(o);
}

__device__ __forceinline__ void sum8_dev(const float* __restrict__ in0, const float* __restrict__ in1,
                                         bf16* __restrict__ out, int blk, int tid) {
  int i = (blk * 256 + tid) * 8;
  float4 a0 = *reinterpret_cast<const float4*>(in0 + i);
  float4 b0 = *reinterpret_cast<const float4*>(in0 + i + 4);
  float4 a1 = *reinterpret_cast<const float4*>(in1 + i);
  float4 b1 = *reinterpret_cast<const float4*>(in1 + i + 4);
  bf16 o[8] __attribute__((aligned(16)));
  o[0] = (bf16)(a0.x + a1.x); o[1] = (bf16)(a0.y + a1.y);
  o[2] = (bf16)(a0.z + a1.z); o[3] = (bf16)(a0.w + a1.w);
  o[4] = (bf16)(b0.x + b1.x); o[5] = (bf16)(b0.y + b1.y);
  o[6] = (bf16)(b0.z + b1.z); o[7] = (bf16)(b0.w + b1.w);
  *reinterpret_cast<uint4*>(out + i) = *reinterpret_cast<const uint4*>(o);
}

__global__ __launch_bounds__(256) void prep_kernel(const float* __restrict__ x,
                                                   const float* __restrict__ Wq,
                                                   const float* __restrict__ Wk,
                                                   const float* __restrict__ Wv,
                                                   const float* __restrict__ Wo,
                                                   const float* __restrict__ Wdn,
                                                   const float* __restrict__ Wuk,
                                                   const float* __restrict__ Wuv,
                                                   bf16* xbf, bf16* WqT, bf16* WoT, bf16* WdnT,
                                                   bf16* WukT, bf16* WuvT, bf16* Wkv) {
  __shared__ float tile[32][33];
  int id = blockIdx.x, tid = threadIdx.x;
  if (id < 2048) { cvt8_dev(x, xbf, id, tid); return; }
  id -= 2048;
  if (id < 512) { sum8_dev(Wk, Wv, Wkv, id, tid); return; }   // Wkv = bf16(Wk+Wv) row-major
  id -= 512;
  if (id < 1024) { transpose_dev(Wq, WqT, 1024, 1024, (id & 31) * 32, (id >> 5) * 32, tid, tile); return; }
  id -= 1024;
  if (id < 1024) { transpose_dev(Wo, WoT, 1024, 1024, (id & 31) * 32, (id >> 5) * 32, tid, tile); return; }
  id -= 1024;
  if (id < 256) { transpose_dev(Wdn, WdnT, 1024, 256, (id & 7) * 32, (id >> 3) * 32, tid, tile); return; }
  id -= 256;
  if (id < 256) { transpose_dev(Wuk, WukT, 256, 1024, (id & 31) * 32, (id >> 5) * 32, tid, tile); return; }
  id -= 256;
  transpose_dev(Wuv, WuvT, 256, 1024, (id & 31) * 32, (id >> 5) * 32, tid, tile);
}

// ================= 128x64 MFMA GEMM core, BK=64, XOR-swizzled LDS, 2-phase dbuf =================
// setprio around MFMA clusters: +5.7 us fleet-wide (r16 vs r17 controlled A/B).
// EPI: 0 = bf16 row-major stride DM; 3 = f32 stride DM; 7 = bf16 row-major stride MTOK
template <int EPI>
__device__ __forceinline__ void gemm_core(const bf16* __restrict__ A, const bf16* __restrict__ Bt,
                                          bf16* __restrict__ O1, float* __restrict__ Of,
                                          int K, int bx, int by, bf16* As, bf16* Bs) {
  const int tid = threadIdx.x;
  const int lane = tid & 63;
  const int wv = tid >> 6;
  const int wr = wv >> 1, wc = wv & 1;
  const int row0 = bx * 128, col0 = by * 64;
  const int l15 = lane & 15;
  const int lg = lane >> 4;

  const int r0 = tid >> 3;
  const int ccs = (tid & 7) ^ (r0 & 7);          // pre-swizzled global chunk
  const bf16* aS = A + (size_t)(row0 + r0) * K + ccs * 8;
  const bf16* bS = Bt + (size_t)(col0 + r0) * K + ccs * 8;
  const int dA = tid * 8;

#pragma unroll
  for (int i = 0; i < 4; ++i) gload16(aS + (size_t)(32 * i) * K, As + dA + 2048 * i);
#pragma unroll
  for (int j = 0; j < 2; ++j) gload16(bS + (size_t)(32 * j) * K, Bs + dA + 2048 * j);
  aS += 64; bS += 64;

  int aoff[4][2], boff[2][2];
#pragma unroll
  for (int m = 0; m < 4; ++m) {
    int ra = wr * 64 + m * 16 + l15;
#pragma unroll
    for (int kk = 0; kk < 2; ++kk)
      aoff[m][kk] = ra * 64 + (((kk * 4 + lg) ^ (ra & 7)) * 8);
  }
#pragma unroll
  for (int n = 0; n < 2; ++n) {
    int rb = wc * 32 + n * 16 + l15;
#pragma unroll
    for (int kk = 0; kk < 2; ++kk)
      boff[n][kk] = rb * 64 + (((kk * 4 + lg) ^ (rb & 7)) * 8);
  }

  f32x4 acc[4][2] = {};
  int cur = 0;
  for (int k0 = 0; k0 < K; k0 += 64) {
    __syncthreads();
    if (k0 + 64 < K) {
      const int nxA = (cur ^ 1) * 8192, nxB = (cur ^ 1) * 4096;
#pragma unroll
      for (int i = 0; i < 4; ++i) gload16(aS + (size_t)(32 * i) * K, As + nxA + dA + 2048 * i);
#pragma unroll
      for (int j = 0; j < 2; ++j) gload16(bS + (size_t)(32 * j) * K, Bs + nxB + dA + 2048 * j);
      aS += 64; bS += 64;
    }
    const bf16* Ab = As + cur * 8192;
    const bf16* Bb = Bs + cur * 4096;
    bf16x8 af[4][2], bfr[2][2];
#pragma unroll
    for (int m = 0; m < 4; ++m)
#pragma unroll
      for (int kk = 0; kk < 2; ++kk)
        af[m][kk] = *reinterpret_cast<const bf16x8*>(&Ab[aoff[m][kk]]);
#pragma unroll
    for (int n = 0; n < 2; ++n)
#pragma unroll
      for (int kk = 0; kk < 2; ++kk)
        bfr[n][kk] = *reinterpret_cast<const bf16x8*>(&Bb[boff[n][kk]]);
    __builtin_amdgcn_s_setprio(1);
#pragma unroll
    for (int kk = 0; kk < 2; ++kk)
#pragma unroll
      for (int m = 0; m < 4; ++m)
#pragma unroll
        for (int n = 0; n < 2; ++n)
          acc[m][n] = __builtin_amdgcn_mfma_f32_16x16x32_bf16(af[m][kk], bfr[n][kk], acc[m][n], 0, 0, 0);
    __builtin_amdgcn_s_setprio(0);
    cur ^= 1;
  }

  const int rbase = row0 + wr * 64 + (lane >> 4) * 4;
  const int cbase = col0 + wc * 32 + l15;
#pragma unroll
  for (int m = 0; m < 4; ++m) {
#pragma unroll
    for (int n = 0; n < 2; ++n) {
      const int cc = cbase + n * 16;
      if constexpr (EPI == 0) {
#pragma unroll
        for (int r = 0; r < 4; ++r)
          O1[(size_t)(rbase + m * 16 + r) * DM + cc] = (bf16)acc[m][n][r];
      } else if constexpr (EPI == 3) {
#pragma unroll
        for (int r = 0; r < 4; ++r)
          Of[(size_t)(rbase + m * 16 + r) * DM + cc] = acc[m][n][r];
      } else {  // EPI == 7: [d][tok], stride MTOK
#pragma unroll
        for (int r = 0; r < 4; ++r)
          O1[(size_t)(rbase + m * 16 + r) * MTOK + cc] = (bf16)acc[m][n][r];
      }
    }
  }
}

// ================= 64x64 MFMA GEMM core (latent), BK=64, swizzled =================
__device__ __forceinline__ void gemm64_lat(const bf16* __restrict__ A, const bf16* __restrict__ Bt,
                                           bf16* __restrict__ O1, float* __restrict__ Of,
                                           int K, int bx, int by, bf16* As, bf16* Bs) {
  const int tid = threadIdx.x;
  const int lane = tid & 63;
  const int wv = tid >> 6;
  const int wr = wv >> 1, wc = wv & 1;
  const int row0 = bx * 64, col0 = by * 64;
  const int l15 = lane & 15;
  const int lg = lane >> 4;

  const int r0 = tid >> 3;
  const int ccs = (tid & 7) ^ (r0 & 7);
  const bf16* aS = A + (size_t)(row0 + r0) * K + ccs * 8;
  const bf16* bS = Bt + (size_t)(col0 + r0) * K + ccs * 8;
  const int dA = tid * 8;

#pragma unroll
  for (int j = 0; j < 2; ++j) {
    gload16(aS + (size_t)(32 * j) * K, As + dA + 2048 * j);
    gload16(bS + (size_t)(32 * j) * K, Bs + dA + 2048 * j);
  }
  aS += 64; bS += 64;

  int aoff[2][2], boff[2][2];
#pragma unroll
  for (int m = 0; m < 2; ++m) {
    int ra = wr * 32 + m * 16 + l15;
    int rb = wc * 32 + m * 16 + l15;
#pragma unroll
    for (int kk = 0; kk < 2; ++kk) {
      aoff[m][kk] = ra * 64 + (((kk * 4 + lg) ^ (ra & 7)) * 8);
      boff[m][kk] = rb * 64 + (((kk * 4 + lg) ^ (rb & 7)) * 8);
    }
  }

  f32x4 acc[2][2] = {};
  int cur = 0;
  for (int k0 = 0; k0 < K; k0 += 64) {
    __syncthreads();
    if (k0 + 64 < K) {
      const int nx = (cur ^ 1) * 4096;
#pragma unroll
      for (int j = 0; j < 2; ++j) {
        gload16(aS + (size_t)(32 * j) * K, As + nx + dA + 2048 * j);
        gload16(bS + (size_t)(32 * j) * K, Bs + nx + dA + 2048 * j);
      }
      aS += 64; bS += 64;
    }
    const bf16* Ab = As + cur * 4096;
    const bf16* Bb = Bs + cur * 4096;
    bf16x8 af[2][2], bfr[2][2];
#pragma unroll
    for (int m = 0; m < 2; ++m)
#pragma unroll
      for (int kk = 0; kk < 2; ++kk) {
        af[m][kk] = *reinterpret_cast<const bf16x8*>(&Ab[aoff[m][kk]]);
        bfr[m][kk] = *reinterpret_cast<const bf16x8*>(&Bb[boff[m][kk]]);
      }
    __builtin_amdgcn_s_setprio(1);
#pragma unroll
    for (int kk = 0; kk < 2; ++kk)
#pragma unroll
      for (int m = 0; m < 2; ++m)
#pragma unroll
        for (int n = 0; n < 2; ++n)
          acc[m][n] = __builtin_amdgcn_mfma_f32_16x16x32_bf16(af[m][kk], bfr[n][kk], acc[m][n], 0, 0, 0);
    __builtin_amdgcn_s_setprio(0);
    cur ^= 1;
  }

  const int rbase = row0 + wr * 32 + (lane >> 4) * 4;
  const int cbase = col0 + wc * 32 + l15;
#pragma unroll
  for (int m = 0; m < 2; ++m)
#pragma unroll
    for (int n = 0; n < 2; ++n)
#pragma unroll
      for (int r = 0; r < 4; ++r) {
        float v = acc[m][n][r];
        O1[(size_t)(rbase + m * 16 + r) * DL + (cbase + n * 16)] = (bf16)v;
        Of[(size_t)(rbase + m * 16 + r) * DL + (cbase + n * 16)] = v;
      }
}

// q = x @ Wq (512) + WkvdT = Wdn^T @ (Wk+Wv)^T (32, hidden inside); XCD-swizzled
__global__ __launch_bounds__(256) void gemm_q_w(const bf16* __restrict__ xbf,
                                                const bf16* __restrict__ WqT, bf16* qbf,
                                                const bf16* __restrict__ WdnT,
                                                const bf16* __restrict__ Wkv, bf16* WkvdT) {
  __shared__ __align__(16) bf16 As[2 * 8192];
  __shared__ __align__(16) bf16 Bs[2 * 4096];
  int id = xcd_swz(blockIdx.x, 544);
  if (id < 32)
    gemm_core<0>(WdnT, Wkv, WkvdT, nullptr, DM, id >> 4, id & 15, As, Bs);
  else {
    int j = id - 32;
    gemm_core<0>(xbf, WqT, qbf, nullptr, DM, j >> 4, j & 15, As, Bs);
  }
}

// latent = x @ Wkvd : 64x64 tiles -> 64x4 = 256 blocks (1/CU)
__global__ __launch_bounds__(256) void gemm_latent(const bf16* __restrict__ xbf,
                                                   const bf16* __restrict__ WkvdT,
                                                   bf16* latbf, float* out_lat) {
  __shared__ __align__(16) bf16 As[2 * 4096];
  __shared__ __align__(16) bf16 Bs[2 * 4096];
  int id = xcd_swz(blockIdx.x, 256);
  gemm64_lat(xbf, WkvdT, latbf, out_lat, DM, id >> 2, id & 3, As, Bs);
}

// L4: ids 0-511: k_rec = latent @ Wuk ; ids 512-1023: vT = Wuv^T @ latent^T
__global__ __launch_bounds__(256) void gemm_up(const bf16* __restrict__ latbf,
                                               const bf16* __restrict__ WukT,
                                               const bf16* __restrict__ WuvT,
                                               bf16* kbuf, bf16* vT) {
  __shared__ __align__(16) bf16 As[2 * 8192];
  __shared__ __align__(16) bf16 Bs[2 * 4096];
  int id = xcd_swz(blockIdx.x, 1024);
  if (id < 512)
    gemm_core<0>(latbf, WukT, kbuf, nullptr, DL, id >> 4, id & 15, As, Bs);
  else {
    int j = id - 512;
    gemm_core<7>(WuvT, latbf, vT, nullptr, DL, j >> 6, j & 63, As, Bs);
  }
}

// out0 = ctx @ Wo : N=1024 -> 512 blocks
__global__ __launch_bounds__(256) void gemm_out(const bf16* __restrict__ ctx,
                                                const bf16* __restrict__ WoT, float* out0) {
  __shared__ __align__(16) bf16 As[2 * 8192];
  __shared__ __align__(16) bf16 Bs[2 * 4096];
  int id = xcd_swz(blockIdx.x, 512);
  gemm_core<3>(ctx, WoT, nullptr, out0, DM, id >> 4, id & 15, As, Bs);
}

// ====== flash attention: 16 waves x 256 q/block, KVBLK=256 (4 sub-tiles per barrier) ======
// Barrier count 16 -> 8; LDS = 64+64+32 = 160 KB (full CU budget; grid = 1 block/CU anyway).
__global__ __launch_bounds__(1024) void attn_kernel(const bf16* __restrict__ Q,
                                                    const bf16* __restrict__ Kr,
                                                    const bf16* __restrict__ Vt,
                                                    bf16* __restrict__ Ctx) {
  __shared__ __align__(16) bf16 Ks[2 * 16384];  // [dbuf][256 keys x 64 d], swizzled
  __shared__ __align__(16) bf16 Vs[2 * 16384];  // [dbuf][64 d x 256 keys], swizzled
  __shared__ __align__(16) bf16 Ps[16384];      // 16 waves x 16 q x 64 keys
  const int work = xcd_swz(blockIdx.x, SEQ / 256 * NH * NB);   // 256
  const int qt = work & 7, h = (work >> 3) & 15, b = work >> 7;
  const int tid = threadIdx.x, lane = tid & 63, wv = tid >> 6;  // wv 0..15
  const int l15 = lane & 15, lg = lane >> 4;
  const int qbase = qt * 256 + wv * 16;
  const size_t tok0 = (size_t)b * SEQ;

  bf16x8 qf[2];
  {
    const bf16* qp = Q + (tok0 + qbase + l15) * DM + h * HD + lg * 8;
    qf[0] = *reinterpret_cast<const bf16x8*>(qp);
    qf[1] = *reinterpret_cast<const bf16x8*>(qp + 32);
  }

  // staging: tid<512 -> K (4 chunks: rows r0s + 64s); else V (4 chunks: keys + 64s)
  const int cS = tid & 511;
  const int r0s = cS >> 3;
  const int cc0 = (cS & 7) ^ (r0s & 7);
  const bool isK = tid < 512;
  const bf16* src0 = isK ? (Kr + (tok0 + r0s) * DM + h * HD + cc0 * 8)
                         : (Vt + (size_t)(h * HD + r0s) * MTOK + tok0 + cc0 * 8);
  bf16* const dstBase = isK ? Ks : Vs;
  const size_t subStep = isK ? (size_t)64 * DM : 64;    // sub-tile source stride
  const size_t stepSrc = isK ? (size_t)256 * DM : 256;  // per-period advance
  const int d0 = cS * 8;

  // prologue: stage period 0 (4 sub-tiles) into buf 0
#pragma unroll
  for (int s = 0; s < 4; ++s) gload16(src0 + s * subStep, dstBase + s * 4096 + d0);
  src0 += stepSrc;

  int koff[2][4], poffw[4], poffr[2];
  const int hsw = l15 & 7;
#pragma unroll
  for (int ks = 0; ks < 2; ++ks)
#pragma unroll
    for (int nf = 0; nf < 4; ++nf) {
      int row = nf * 16 + l15;
      koff[ks][nf] = row * 64 + (((ks * 4 + lg) ^ (row & 7)) * 8);
    }
  const int psBase = wv * 1024 + l15 * 64;
#pragma unroll
  for (int nf = 0; nf < 4; ++nf)
    poffw[nf] = psBase + (((nf * 2 + (lg >> 1)) ^ hsw) * 8) + (lg & 1) * 4;
#pragma unroll
  for (int ks = 0; ks < 2; ++ks)
    poffr[ks] = psBase + (((ks * 4 + lg) ^ hsw) * 8);

  bf16x8 ones;
#pragma unroll
  for (int j = 0; j < 8; ++j) ones[j] = (bf16)1.0f;

  f32x4 oacc[4] = {};
  f32x4 lacc = {};
  float dec[4][4];
  const float DEC2C = (1.0f / 32.0f) * LOG2E;
  const float NC2 = -1.0e-4f * LOG2E;
  const float E64 = 0.99362048f, IE64 = 1.00642051f;
  const int ib = -qbase - l15 + lg * 4;

  // dec for tile key0 = 0
#pragma unroll
  for (int nf = 0; nf < 4; ++nf)
#pragma unroll
    for (int r = 0; r < 4; ++r) {
      float df = (float)(ib + nf * 16 + r);
      dec[nf][r] = DEC2C * fast_exp2(NC2 * fabsf(df));
    }

  auto upd_dec = [&](int key0) {  // advance dec from tile (key0-64) to tile key0
    bool before = (key0 + 63 < qbase);
    bool afterp = (key0 >= qbase + 79);
    if (!before && !afterp) {
#pragma unroll
      for (int nf = 0; nf < 4; ++nf)
#pragma unroll
        for (int r = 0; r < 4; ++r) {
          float df = (float)(key0 + ib + nf * 16 + r);
          dec[nf][r] = DEC2C * fast_exp2(NC2 * fabsf(df));
        }
    } else {
      float mlt = before ? IE64 : E64;
#pragma unroll
      for (int nf = 0; nf < 4; ++nf)
#pragma unroll
        for (int r = 0; r < 4; ++r) dec[nf][r] *= mlt;
    }
  };

  // one 64-key sub-tile: QK -> softmax(Ps round-trip) -> PV + lsum (proven body)
  auto body = [&](int kb) {
    f32x4 sc[4] = {};
    __builtin_amdgcn_s_setprio(1);
#pragma unroll
    for (int ks = 0; ks < 2; ++ks)
#pragma unroll
      for (int nf = 0; nf < 4; ++nf) {
        bf16x8 kf = *reinterpret_cast<const bf16x8*>(&Ks[kb + koff[ks][nf]]);
        sc[nf] = __builtin_amdgcn_mfma_f32_16x16x32_bf16(kf, qf[ks], sc[nf], 0, 0, 0);
      }
    __builtin_amdgcn_s_setprio(0);
#pragma unroll
    for (int nf = 0; nf < 4; ++nf) {
      bf16 t4[4] __attribute__((aligned(8)));
#pragma unroll
      for (int r = 0; r < 4; ++r) t4[r] = (bf16)fast_exp2(sc[nf][r] * dec[nf][r]);
      *reinterpret_cast<uint2*>(&Ps[poffw[nf]]) = *reinterpret_cast<const uint2*>(t4);
    }
    bf16x8 pb[2];
    pb[0] = *reinterpret_cast<const bf16x8*>(&Ps[poffr[0]]);
    pb[1] = *reinterpret_cast<const bf16x8*>(&Ps[poffr[1]]);
    __builtin_amdgcn_s_setprio(1);
#pragma unroll
    for (int ks = 0; ks < 2; ++ks) {
#pragma unroll
      for (int nf = 0; nf < 4; ++nf) {
        bf16x8 vf = *reinterpret_cast<const bf16x8*>(&Vs[kb + koff[ks][nf]]);
        oacc[nf] = __builtin_amdgcn_mfma_f32_16x16x32_bf16(vf, pb[ks], oacc[nf], 0, 0, 0);
      }
      lacc = __builtin_amdgcn_mfma_f32_16x16x32_bf16(ones, pb[ks], lacc, 0, 0, 0);
    }
    __builtin_amdgcn_s_setprio(0);
  };

  int cur = 0;
  for (int p = 0; p < 8; ++p) {
    __syncthreads();   // buf[cur] staged; buf[cur^1] reads drained
    if (p + 1 < 8) {
      const int nx = (cur ^ 1) * 16384;
#pragma unroll
      for (int s = 0; s < 4; ++s) gload16(src0 + s * subStep, dstBase + nx + s * 4096 + d0);
      src0 += stepSrc;
    }
    const int kb = cur * 16384;
#pragma unroll
    for (int s = 0; s < 4; ++s) {
      body(kb + s * 4096);                    // keys [256p + 64s, 256p + 64s + 64)
      if (p + 1 < 8 || s < 3) upd_dec(p * 256 + 64 * (s + 1));
    }
    cur ^= 1;
  }

  const float inv = 1.0f / lacc[0];
#pragma unroll
  for (int nf = 0; nf < 4; ++nf) {
    bf16 o4[4] __attribute__((aligned(8)));
#pragma unroll
    for (int r = 0; r < 4; ++r) o4[r] = (bf16)(oacc[nf][r] * inv);
    *reinterpret_cast<uint2*>(Ctx + (tok0 + qbase + l15) * DM + h * HD + nf * 16 + lg * 4) =
        *reinterpret_cast<const uint2*>(o4);
  }
}

// ================= launch =================
extern "C" void kernel_launch(void* const* d_in, const int* in_sizes, int n_in,
                              void* d_out, int out_size, void* d_ws, size_t ws_size,
                              hipStream_t stream) {
  const float* x   = (const float*)d_in[0];
  const float* Wq  = (const float*)d_in[1];
  const float* Wk  = (const float*)d_in[2];
  const float* Wv  = (const float*)d_in[3];
  const float* Wo  = (const float*)d_in[4];
  const float* Wdn = (const float*)d_in[5];
  const float* Wuk = (const float*)d_in[6];
  const float* Wuv = (const float*)d_in[7];
  float* out0 = (float*)d_out;                     // [4096][1024] f32
  float* out_lat = out0 + (size_t)MTOK * DM;       // [4096][256]  f32

  char* ws = (char*)d_ws;
  const size_t MB = 1u << 20;
  bf16* xbf   = (bf16*)(ws + 0);            // 8 MiB; reused as ctx
  bf16* qbf   = (bf16*)(ws + 8 * MB);       // 8 MiB
  bf16* kbuf  = (bf16*)(ws + 16 * MB);      // 8 MiB: k_rec (L4+); Wkv alias before L4
  bf16* Wkv   = kbuf;                       //   [16,18) Wkv bf16 [1024][1024] (dead after L2)
  bf16* WkvdT = (bf16*)(ws + 18 * MB);      //   [18,18.5) WkvdT [256][1024] (dead after L3)
  bf16* vT    = (bf16*)(ws + 24 * MB);      // 8 MiB: v_rec^T [1024][4096]
  bf16* latbf = (bf16*)(ws + 32 * MB);      // 2 MiB [4096][256]
  bf16* WqT   = (bf16*)(ws + 34 * MB);      // 2 MiB [1024][1024]
  bf16* WoT   = (bf16*)(ws + 36 * MB);      // 2 MiB
  bf16* WukT  = (bf16*)(ws + 38 * MB);      // 512 KiB [1024][256]
  bf16* WuvT  = (bf16*)(ws + 38 * MB + 512 * 1024);  // 512 KiB [1024][256]
  bf16* WdnT  = (bf16*)(ws + 39 * MB);      // 512 KiB [256][1024]
  bf16* ctx   = xbf;

  // L1: prep (memory-only; 32x32 transposes + sum8)
  prep_kernel<<<5376, 256, 0, stream>>>(x, Wq, Wk, Wv, Wo, Wdn, Wuk, Wuv,
                                        xbf, WqT, WoT, WdnT, WukT, WuvT, Wkv);
  // L2: q = x@Wq (512) + WkvdT = Wdn^T@(Wk+Wv)^T (32, hidden)
  gemm_q_w<<<544, 256, 0, stream>>>(xbf, WqT, qbf, WdnT, Wkv, WkvdT);
  // L3: latent = x @ Wkvd (64x64 tiles, 256 blocks)
  gemm_latent<<<256, 256, 0, stream>>>(xbf, WkvdT, latbf, out_lat);
  // L4: k_rec = latent @ Wuk ; vT = Wuv^T @ latent^T
  gemm_up<<<1024, 256, 0, stream>>>(latbf, WukT, WuvT, kbuf, vT);
  // L5: attention (16 waves, 256 q/block, KVBLK=256, 256 blocks)
  attn_kernel<<<256, 1024, 0, stream>>>(qbf, kbuf, vT, ctx);
  // L6: out0 = ctx @ Wo
  gemm_out<<<512, 256, 0, stream>>>(ctx, WoT, out0);

  (void)in_sizes; (void)n_in; (void)out_size; (void)ws_size;
}